// Round 1
// baseline (3554.482 us; speedup 1.0000x reference)
//
#include <hip/hip_runtime.h>
#include <math.h>

#define DM 768
#define NH 12
#define DK 64
#define DFF 3072
#define BB 2
#define SS 2048
#define NL 2
#define NEGV (-1000000000.0f)

// ---------------- embed + positional ----------------
__global__ __launch_bounds__(256) void embed_kernel(
    const int* __restrict__ toks, const float* __restrict__ emb,
    const float* __restrict__ pos, float* __restrict__ x)
{
    int rs = blockIdx.x;              // b*SS + s
    int s = rs & (SS - 1);
    int tok = toks[rs];
    int t = threadIdx.x;
    const float* e = emb + (size_t)tok * DM;
    const float* p = pos + (size_t)s * DM;
    float* xr = x + (size_t)rs * DM;
#pragma unroll
    for (int i = 0; i < 3; ++i) {
        int c = t + 256 * i;
        xr[c] = e[c] + p[c];
    }
}

// ---------------- generic f32 GEMM: C[M,N] = A[M,K] @ W[K,N] (+bias, relu) ----
// 64x64 tile, BK=16, 256 threads, 4x4 micro-tile per thread.
__global__ __launch_bounds__(256) void gemm_kernel(
    const float* __restrict__ A, const float* __restrict__ W,
    const float* __restrict__ bias, float* __restrict__ C,
    int M, int N, int K, int relu)
{
    __shared__ float As[16][64];   // [k][m]
    __shared__ float Ws[16][64];   // [k][n]
    int tid = threadIdx.x;
    int tx = tid & 15;             // n
    int ty = tid >> 4;             // m
    int row0 = blockIdx.y * 64;
    int col0 = blockIdx.x * 64;
    float c[4][4] = {};
    for (int k0 = 0; k0 < K; k0 += 16) {
        {
            int r = tid >> 2;
            int kk = (tid & 3) * 4;
            const float4 a4 = *(const float4*)(&A[(size_t)(row0 + r) * K + k0 + kk]);
            As[kk + 0][r] = a4.x; As[kk + 1][r] = a4.y;
            As[kk + 2][r] = a4.z; As[kk + 3][r] = a4.w;
        }
        {
            int kk = tid >> 4;
            int n4 = (tid & 15) * 4;
            const float4 w4 = *(const float4*)(&W[(size_t)(k0 + kk) * N + col0 + n4]);
            Ws[kk][n4 + 0] = w4.x; Ws[kk][n4 + 1] = w4.y;
            Ws[kk][n4 + 2] = w4.z; Ws[kk][n4 + 3] = w4.w;
        }
        __syncthreads();
#pragma unroll
        for (int kk = 0; kk < 16; ++kk) {
            float a[4], b[4];
#pragma unroll
            for (int i = 0; i < 4; ++i) a[i] = As[kk][ty + 16 * i];
#pragma unroll
            for (int j = 0; j < 4; ++j) b[j] = Ws[kk][tx + 16 * j];
#pragma unroll
            for (int i = 0; i < 4; ++i)
#pragma unroll
                for (int j = 0; j < 4; ++j)
                    c[i][j] += a[i] * b[j];
        }
        __syncthreads();
    }
#pragma unroll
    for (int i = 0; i < 4; ++i) {
        int row = row0 + ty + 16 * i;
#pragma unroll
        for (int j = 0; j < 4; ++j) {
            int col = col0 + tx + 16 * j;
            float v = c[i][j];
            if (bias) v += bias[col];
            if (relu) v = fmaxf(v, 0.0f);
            C[(size_t)row * N + col] = v;
        }
    }
}

// ---------------- scores: attn[b,h,q,k] = mask(0.125 * q . k) ----------------
// grid (S/64, S/64, B*NH); NT GEMM with K=64
__global__ __launch_bounds__(256) void scores_kernel(
    const float* __restrict__ q, const float* __restrict__ k,
    const int* __restrict__ amask, float* __restrict__ attnL)
{
    __shared__ float Qs[16][64];   // [kk][qrow]
    __shared__ float Ks[16][64];   // [kk][krow]
    int tid = threadIdx.x;
    int tx = tid & 15;
    int ty = tid >> 4;
    int row0 = blockIdx.y * 64;    // q pos
    int col0 = blockIdx.x * 64;    // k pos
    int bh = blockIdx.z;
    int b = bh / NH;
    int h = bh % NH;
    const float* qb = q + ((size_t)b * SS) * DM + h * DK;
    const float* kb = k + ((size_t)b * SS) * DM + h * DK;
    float c[4][4] = {};
    for (int k0 = 0; k0 < DK; k0 += 16) {
        {
            int r = tid >> 2;
            int kk = (tid & 3) * 4;
            const float4 a4 = *(const float4*)(&qb[(size_t)(row0 + r) * DM + k0 + kk]);
            Qs[kk + 0][r] = a4.x; Qs[kk + 1][r] = a4.y;
            Qs[kk + 2][r] = a4.z; Qs[kk + 3][r] = a4.w;
        }
        {
            int r = tid >> 2;
            int kk = (tid & 3) * 4;
            const float4 a4 = *(const float4*)(&kb[(size_t)(col0 + r) * DM + k0 + kk]);
            Ks[kk + 0][r] = a4.x; Ks[kk + 1][r] = a4.y;
            Ks[kk + 2][r] = a4.z; Ks[kk + 3][r] = a4.w;
        }
        __syncthreads();
#pragma unroll
        for (int kk = 0; kk < 16; ++kk) {
            float a[4], bb[4];
#pragma unroll
            for (int i = 0; i < 4; ++i) a[i] = Qs[kk][ty + 16 * i];
#pragma unroll
            for (int j = 0; j < 4; ++j) bb[j] = Ks[kk][tx + 16 * j];
#pragma unroll
            for (int i = 0; i < 4; ++i)
#pragma unroll
                for (int j = 0; j < 4; ++j)
                    c[i][j] += a[i] * bb[j];
        }
        __syncthreads();
    }
    float* ab = attnL + (size_t)bh * SS * SS;
    const int* am = amask + b * SS;
#pragma unroll
    for (int i = 0; i < 4; ++i) {
        int qpos = row0 + ty + 16 * i;
#pragma unroll
        for (int j = 0; j < 4; ++j) {
            int kpos = col0 + tx + 16 * j;
            float s = c[i][j] * 0.125f;
            // FAITHFUL to reference: keep score where (pad || future), else -1e9
            bool keep = (am[kpos] == 0) || (kpos > qpos);
            ab[(size_t)qpos * SS + kpos] = keep ? s : NEGV;
        }
    }
}

// ---------------- softmax in-place over rows of attnL ----------------
__global__ __launch_bounds__(256) void softmax_kernel(float* __restrict__ attnL)
{
    float* row = attnL + (size_t)blockIdx.x * SS;
    int t = threadIdx.x;
    __shared__ float red[256];
    float vals[8];
    float m = -INFINITY;
#pragma unroll
    for (int i = 0; i < 8; ++i) {
        vals[i] = row[t + 256 * i];
        m = fmaxf(m, vals[i]);
    }
    red[t] = m;
    __syncthreads();
    for (int s = 128; s > 0; s >>= 1) {
        if (t < s) red[t] = fmaxf(red[t], red[t + s]);
        __syncthreads();
    }
    m = red[0];
    __syncthreads();
    float sum = 0.0f;
#pragma unroll
    for (int i = 0; i < 8; ++i) {
        vals[i] = expf(vals[i] - m);
        sum += vals[i];
    }
    red[t] = sum;
    __syncthreads();
    for (int s = 128; s > 0; s >>= 1) {
        if (t < s) red[t] += red[t + s];
        __syncthreads();
    }
    float inv = 1.0f / red[0];
#pragma unroll
    for (int i = 0; i < 8; ++i)
        row[t + 256 * i] = vals[i] * inv;
}

// ---------------- ctx: ctx[b,q,h*64+d] = sum_k attn[b,h,q,k] * v[b,k,h*64+d] --
// grid (S/64, B*NH); 64q x 64d tile, K loop over S by 16
__global__ __launch_bounds__(256) void ctx_kernel(
    const float* __restrict__ attnL, const float* __restrict__ v,
    float* __restrict__ ctx)
{
    __shared__ float As[16][64];   // [kk][qrow]
    __shared__ float Vs[16][64];   // [kk][d]
    int tid = threadIdx.x;
    int tx = tid & 15;
    int ty = tid >> 4;
    int row0 = blockIdx.x * 64;    // q pos
    int bh = blockIdx.y;
    int b = bh / NH;
    int h = bh % NH;
    const float* ab = attnL + (size_t)bh * SS * SS;
    const float* vb = v + ((size_t)b * SS) * DM + h * DK;
    float c[4][4] = {};
    for (int k0 = 0; k0 < SS; k0 += 16) {
        {
            int r = tid >> 2;
            int kk = (tid & 3) * 4;
            const float4 a4 = *(const float4*)(&ab[(size_t)(row0 + r) * SS + k0 + kk]);
            As[kk + 0][r] = a4.x; As[kk + 1][r] = a4.y;
            As[kk + 2][r] = a4.z; As[kk + 3][r] = a4.w;
        }
        {
            int kk = tid >> 4;
            int n4 = (tid & 15) * 4;
            const float4 w4 = *(const float4*)(&vb[(size_t)(k0 + kk) * DM + n4]);
            Vs[kk][n4 + 0] = w4.x; Vs[kk][n4 + 1] = w4.y;
            Vs[kk][n4 + 2] = w4.z; Vs[kk][n4 + 3] = w4.w;
        }
        __syncthreads();
#pragma unroll
        for (int kk = 0; kk < 16; ++kk) {
            float a[4], bb[4];
#pragma unroll
            for (int i = 0; i < 4; ++i) a[i] = As[kk][ty + 16 * i];
#pragma unroll
            for (int j = 0; j < 4; ++j) bb[j] = Vs[kk][tx + 16 * j];
#pragma unroll
            for (int i = 0; i < 4; ++i)
#pragma unroll
                for (int j = 0; j < 4; ++j)
                    c[i][j] += a[i] * bb[j];
        }
        __syncthreads();
    }
#pragma unroll
    for (int i = 0; i < 4; ++i) {
        int qpos = row0 + ty + 16 * i;
#pragma unroll
        for (int j = 0; j < 4; ++j) {
            int d = tx + 16 * j;
            ctx[((size_t)b * SS + qpos) * DM + h * DK + d] = c[i][j];
        }
    }
}

// ---------------- residual add + layernorm ----------------
__global__ __launch_bounds__(256) void add_ln_kernel(
    const float* __restrict__ a, const float* __restrict__ xin,
    const float* __restrict__ g, const float* __restrict__ bta,
    float* __restrict__ xout)
{
    int row = blockIdx.x;
    int t = threadIdx.x;
    const float* ar = a + (size_t)row * DM;
    const float* xr = xin + (size_t)row * DM;
    float* orow = xout + (size_t)row * DM;
    __shared__ float red[256];
    float v[3];
    float sum = 0.0f;
#pragma unroll
    for (int i = 0; i < 3; ++i) {
        int c = t + 256 * i;
        v[i] = ar[c] + xr[c];
        sum += v[i];
    }
    red[t] = sum;
    __syncthreads();
    for (int s = 128; s > 0; s >>= 1) {
        if (t < s) red[t] += red[t + s];
        __syncthreads();
    }
    float mean = red[0] * (1.0f / DM);
    __syncthreads();
    float sq = 0.0f;
#pragma unroll
    for (int i = 0; i < 3; ++i) {
        float d = v[i] - mean;
        sq += d * d;
    }
    red[t] = sq;
    __syncthreads();
    for (int s = 128; s > 0; s >>= 1) {
        if (t < s) red[t] += red[t + s];
        __syncthreads();
    }
    float inv = 1.0f / sqrtf(red[0] * (1.0f / DM) + 1e-5f);
#pragma unroll
    for (int i = 0; i < 3; ++i) {
        int c = t + 256 * i;
        orow[c] = (v[i] - mean) * inv * g[c] + bta[c];
    }
}

extern "C" void kernel_launch(void* const* d_in, const int* in_sizes, int n_in,
                              void* d_out, int out_size, void* d_ws, size_t ws_size,
                              hipStream_t stream)
{
    const int*   toks  = (const int*)d_in[0];
    const int*   amask = (const int*)d_in[1];
    const float* emb   = (const float*)d_in[2];
    const float* pos   = (const float*)d_in[3];
    const float* wq    = (const float*)d_in[4];
    const float* wk    = (const float*)d_in[5];
    const float* wv    = (const float*)d_in[6];
    const float* wo    = (const float*)d_in[7];
    const float* ln1g  = (const float*)d_in[8];
    const float* ln1b  = (const float*)d_in[9];
    const float* w1    = (const float*)d_in[10];
    const float* b1    = (const float*)d_in[11];
    const float* w2    = (const float*)d_in[12];
    const float* b2    = (const float*)d_in[13];
    const float* ln2g  = (const float*)d_in[14];
    const float* ln2b  = (const float*)d_in[15];

    float* out = (float*)d_out;
    float* ws  = (float*)d_ws;

    const size_t ROWS = (size_t)BB * SS;          // 4096
    const size_t XSZ  = ROWS * DM;                // 3,145,728
    const size_t ATTN_L = (size_t)BB * NH * SS * SS; // 100,663,296

    float* x    = ws;
    float* q    = ws + XSZ;
    float* k    = ws + 2 * XSZ;
    float* v    = ws + 3 * XSZ;
    float* tmp  = ws + 4 * XSZ;
    float* tmp2 = ws + 5 * XSZ;
    float* ff   = ws + 6 * XSZ;                   // 4096 x 3072

    float* attn_out = out + XSZ;

    embed_kernel<<<ROWS, 256, 0, stream>>>(toks, emb, pos, x);

    for (int l = 0; l < NL; ++l) {
        const float* wql = wq + (size_t)l * DM * DM;
        const float* wkl = wk + (size_t)l * DM * DM;
        const float* wvl = wv + (size_t)l * DM * DM;
        const float* wol = wo + (size_t)l * DM * DM;
        const float* w1l = w1 + (size_t)l * DM * DFF;
        const float* w2l = w2 + (size_t)l * DFF * DM;

        dim3 g768(DM / 64, ROWS / 64);
        gemm_kernel<<<g768, 256, 0, stream>>>(x, wql, nullptr, q, ROWS, DM, DM, 0);
        gemm_kernel<<<g768, 256, 0, stream>>>(x, wkl, nullptr, k, ROWS, DM, DM, 0);
        gemm_kernel<<<g768, 256, 0, stream>>>(x, wvl, nullptr, v, ROWS, DM, DM, 0);

        float* attnL = attn_out + (size_t)l * ATTN_L;
        scores_kernel<<<dim3(SS / 64, SS / 64, BB * NH), 256, 0, stream>>>(q, k, amask, attnL);
        softmax_kernel<<<BB * NH * SS, 256, 0, stream>>>(attnL);
        ctx_kernel<<<dim3(SS / 64, BB * NH), 256, 0, stream>>>(attnL, v, tmp);

        gemm_kernel<<<g768, 256, 0, stream>>>(tmp, wol, nullptr, tmp2, ROWS, DM, DM, 0);
        add_ln_kernel<<<ROWS, 256, 0, stream>>>(tmp2, x, ln1g + l * DM, ln1b + l * DM, x);

        gemm_kernel<<<dim3(DFF / 64, ROWS / 64), 256, 0, stream>>>(x, w1l, b1 + l * DFF, ff, ROWS, DFF, DM, 1);
        gemm_kernel<<<g768, 256, 0, stream>>>(ff, w2l, b2 + l * DM, tmp, ROWS, DM, DFF, 0);

        float* xdst = (l == NL - 1) ? out : x;
        add_ln_kernel<<<ROWS, 256, 0, stream>>>(tmp, x, ln2g + l * DM, ln2b + l * DM, xdst);
    }
}

// Round 2
// 1251.915 us; speedup vs baseline: 2.8392x; 2.8392x over previous
//
#include <hip/hip_runtime.h>
#include <math.h>

#define DM 768
#define NH 12
#define DK 64
#define DFF 3072
#define BB 2
#define SS 2048
#define NL 2
#define NEGV (-1000000000.0f)

typedef __attribute__((ext_vector_type(8))) short short8;
typedef __attribute__((ext_vector_type(4))) float f32x4;

__device__ inline unsigned short f2bf(float f) {
    unsigned int u = __float_as_uint(f);
    u += 0x7fffu + ((u >> 16) & 1u);
    return (unsigned short)(u >> 16);
}
__device__ inline float bf2f(unsigned short h) {
    return __uint_as_float(((unsigned int)h) << 16);
}

#define GL16(g, l) __builtin_amdgcn_global_load_lds( \
    (const __attribute__((address_space(1))) void*)(g), \
    (__attribute__((address_space(3))) void*)(l), 16, 0, 0)

// ---------------- embed + positional (f32 + bf16 outputs) ----------------
__global__ __launch_bounds__(256) void embed_kernel(
    const int* __restrict__ toks, const float* __restrict__ emb,
    const float* __restrict__ pos, float* __restrict__ x,
    unsigned short* __restrict__ xb)
{
    int rs = blockIdx.x;
    int s = rs & (SS - 1);
    int tok = toks[rs];
    int t = threadIdx.x;
    const float* e = emb + (size_t)tok * DM;
    const float* p = pos + (size_t)s * DM;
    float* xr = x + (size_t)rs * DM;
    unsigned short* xbr = xb + (size_t)rs * DM;
#pragma unroll
    for (int i = 0; i < 3; ++i) {
        int c = t + 256 * i;
        float v = e[c] + p[c];
        xr[c] = v;
        xbr[c] = f2bf(v);
    }
}

// ---------------- weight transpose-convert: W[K][N] f32 -> WT[N][K] bf16 ----
__global__ __launch_bounds__(256) void transpose_bf16_kernel(
    const float* __restrict__ W, unsigned short* __restrict__ WT, int Kd, int Nd)
{
    __shared__ float tile[32][33];
    int n0 = blockIdx.x * 32, k0 = blockIdx.y * 32;
    int c = threadIdx.x & 31, r = threadIdx.x >> 5;   // r in 0..7
#pragma unroll
    for (int i = 0; i < 32; i += 8)
        tile[r + i][c] = W[(size_t)(k0 + r + i) * Nd + n0 + c];
    __syncthreads();
#pragma unroll
    for (int i = 0; i < 32; i += 8)
        WT[(size_t)(n0 + r + i) * Kd + k0 + c] = f2bf(tile[c][r + i]);
}

// ---------------- MFMA GEMM: C[M,N] = A[M,K](bf16) @ Bt[N,K](bf16)^T --------
// 128x128 tile, BK=32, 256 thr = 4 waves (2x2), 4x4 16x16x32 frags per wave.
// OUT_MODE: 0=f32, 1=bf16, 2=bf16+relu, 3=bf16 V-transposed [b][col][s]
template<int OUT_MODE>
__global__ __launch_bounds__(256) void gemm_bt(
    const unsigned short* __restrict__ A, const unsigned short* __restrict__ Bt,
    const float* __restrict__ bias, void* __restrict__ Cv,
    int K, int lda, int ldb, int ldc)
{
    __shared__ unsigned short As[128 * 32];
    __shared__ unsigned short Bs[128 * 32];
    const int t = threadIdx.x;
    const int row0 = blockIdx.y * 128;
    const int col0 = blockIdx.x * 128;
    const int lane = t & 63, wid = t >> 6;
    const int wr = wid >> 1, wc = wid & 1;
    const int half = lane >> 4, lr = lane & 15;
    f32x4 acc[4][4] = {};

    const int o = t * 16;          // byte offset within a 4KB staging round
    const int srow = o >> 6;       // 0..63
    const int skb = (o & 63) >> 1; // ushort offset within 64B row

    for (int k0 = 0; k0 < K; k0 += 32) {
        GL16(A + (size_t)(row0 + srow) * lda + k0 + skb, (unsigned short*)As + o / 2);
        GL16(A + (size_t)(row0 + 64 + srow) * lda + k0 + skb, (unsigned short*)As + 2048 + o / 2);
        GL16(Bt + (size_t)(col0 + srow) * ldb + k0 + skb, (unsigned short*)Bs + o / 2);
        GL16(Bt + (size_t)(col0 + 64 + srow) * ldb + k0 + skb, (unsigned short*)Bs + 2048 + o / 2);
        __syncthreads();
        short8 af[4], bfr[4];
#pragma unroll
        for (int m = 0; m < 4; ++m)
            af[m] = *(const short8*)&As[(wr * 64 + m * 16 + lr) * 32 + half * 8];
#pragma unroll
        for (int n = 0; n < 4; ++n)
            bfr[n] = *(const short8*)&Bs[(wc * 64 + n * 16 + lr) * 32 + half * 8];
#pragma unroll
        for (int m = 0; m < 4; ++m)
#pragma unroll
            for (int n = 0; n < 4; ++n)
                acc[m][n] = __builtin_amdgcn_mfma_f32_16x16x32_bf16(af[m], bfr[n], acc[m][n], 0, 0, 0);
        __syncthreads();
    }

#pragma unroll
    for (int m = 0; m < 4; ++m) {
#pragma unroll
        for (int n = 0; n < 4; ++n) {
            const int cidx = col0 + wc * 64 + n * 16 + lr;
            const float bv = bias ? bias[cidx] : 0.0f;
#pragma unroll
            for (int j = 0; j < 4; ++j) {
                const int r = row0 + wr * 64 + m * 16 + half * 4 + j;
                float v = acc[m][n][j] + bv;
                if (OUT_MODE == 2) v = fmaxf(v, 0.0f);
                if (OUT_MODE == 0) {
                    ((float*)Cv)[(size_t)r * ldc + cidx] = v;
                } else if (OUT_MODE == 3) {
                    int b = r >> 11, s = r & 2047;
                    ((unsigned short*)Cv)[((size_t)b * DM + cidx) * SS + s] = f2bf(v);
                } else {
                    ((unsigned short*)Cv)[(size_t)r * ldc + cidx] = f2bf(v);
                }
            }
        }
    }
}

// ---------------- scores via MFMA: masked scaled QK^T -> f32 attnL ---------
__global__ __launch_bounds__(256) void scores_mfma(
    const unsigned short* __restrict__ q, const unsigned short* __restrict__ k,
    const int* __restrict__ amask, float* __restrict__ attnL)
{
    __shared__ unsigned short As[128 * 32];
    __shared__ unsigned short Bs[128 * 32];
    const int t = threadIdx.x;
    const int bh = blockIdx.z, b = bh / NH, h = bh % NH;
    const unsigned short* Aq = q + (size_t)b * SS * DM + h * DK;
    const unsigned short* Bk = k + (size_t)b * SS * DM + h * DK;
    const int row0 = blockIdx.y * 128;
    const int col0 = blockIdx.x * 128;
    const int lane = t & 63, wid = t >> 6;
    const int wr = wid >> 1, wc = wid & 1;
    const int half = lane >> 4, lr = lane & 15;
    f32x4 acc[4][4] = {};

    const int o = t * 16;
    const int srow = o >> 6;
    const int skb = (o & 63) >> 1;

#pragma unroll
    for (int k0 = 0; k0 < DK; k0 += 32) {
        GL16(Aq + (size_t)(row0 + srow) * DM + k0 + skb, (unsigned short*)As + o / 2);
        GL16(Aq + (size_t)(row0 + 64 + srow) * DM + k0 + skb, (unsigned short*)As + 2048 + o / 2);
        GL16(Bk + (size_t)(col0 + srow) * DM + k0 + skb, (unsigned short*)Bs + o / 2);
        GL16(Bk + (size_t)(col0 + 64 + srow) * DM + k0 + skb, (unsigned short*)Bs + 2048 + o / 2);
        __syncthreads();
        short8 af[4], bfr[4];
#pragma unroll
        for (int m = 0; m < 4; ++m)
            af[m] = *(const short8*)&As[(wr * 64 + m * 16 + lr) * 32 + half * 8];
#pragma unroll
        for (int n = 0; n < 4; ++n)
            bfr[n] = *(const short8*)&Bs[(wc * 64 + n * 16 + lr) * 32 + half * 8];
#pragma unroll
        for (int m = 0; m < 4; ++m)
#pragma unroll
            for (int n = 0; n < 4; ++n)
                acc[m][n] = __builtin_amdgcn_mfma_f32_16x16x32_bf16(af[m], bfr[n], acc[m][n], 0, 0, 0);
        __syncthreads();
    }

    float* ab = attnL + (size_t)bh * SS * SS;
    const int* am = amask + b * SS;
#pragma unroll
    for (int m = 0; m < 4; ++m) {
#pragma unroll
        for (int n = 0; n < 4; ++n) {
            const int kpos = col0 + wc * 64 + n * 16 + lr;
            const bool pad = (am[kpos] == 0);
#pragma unroll
            for (int j = 0; j < 4; ++j) {
                const int qpos = row0 + wr * 64 + m * 16 + half * 4 + j;
                float s = acc[m][n][j] * 0.125f;
                // FAITHFUL to reference: keep score where (pad || future)
                bool keep = pad || (kpos > qpos);
                ab[(size_t)qpos * SS + kpos] = keep ? s : NEGV;
            }
        }
    }
}

// ---------------- softmax in-place over rows of attnL ----------------
__global__ __launch_bounds__(256) void softmax_kernel(float* __restrict__ attnL)
{
    float* row = attnL + (size_t)blockIdx.x * SS;
    int t = threadIdx.x;
    __shared__ float red[256];
    float vals[8];
    float m = -INFINITY;
#pragma unroll
    for (int i = 0; i < 8; ++i) {
        vals[i] = row[t + 256 * i];
        m = fmaxf(m, vals[i]);
    }
    red[t] = m;
    __syncthreads();
    for (int s = 128; s > 0; s >>= 1) {
        if (t < s) red[t] = fmaxf(red[t], red[t + s]);
        __syncthreads();
    }
    m = red[0];
    __syncthreads();
    float sum = 0.0f;
#pragma unroll
    for (int i = 0; i < 8; ++i) {
        vals[i] = expf(vals[i] - m);
        sum += vals[i];
    }
    red[t] = sum;
    __syncthreads();
    for (int s = 128; s > 0; s >>= 1) {
        if (t < s) red[t] += red[t + s];
        __syncthreads();
    }
    float inv = 1.0f / red[0];
#pragma unroll
    for (int i = 0; i < 8; ++i)
        row[t + 256 * i] = vals[i] * inv;
}

// ---------------- ctx via MFMA: cb[b,s,h*64+d] = attn @ V ------------------
// tile 256(q) x 64(d), BK=32, waves 4x1. A = f32 attn (reg-staged -> bf16 LDS),
// B = vt[b][h*64+d][s] bf16 via global_load_lds.
__global__ __launch_bounds__(256) void ctx_mfma(
    const float* __restrict__ attnL, const unsigned short* __restrict__ vt,
    unsigned short* __restrict__ cb)
{
    __shared__ unsigned short As[256 * 32];  // 16KB
    __shared__ unsigned short Bs[64 * 32];   // 4KB
    const int t = threadIdx.x;
    const int bh = blockIdx.y, b = bh / NH, h = bh % NH;
    const int row0 = blockIdx.x * 256;
    const float* Ag = attnL + (size_t)bh * SS * SS;
    const unsigned short* Bg = vt + ((size_t)b * DM + h * DK) * SS;
    const int lane = t & 63, wid = t >> 6;
    const int wr = wid;
    const int half = lane >> 4, lr = lane & 15;
    f32x4 acc[4][4] = {};

    const int o = t * 16;
    const int srow = o >> 6;       // 0..63
    const int skb = (o & 63) >> 1;

    for (int k0 = 0; k0 < SS; k0 += 32) {
        GL16(Bg + (size_t)srow * SS + k0 + skb, (unsigned short*)Bs + o / 2);
#pragma unroll
        for (int rr = 0; rr < 8; ++rr) {
            const int o4 = (rr * 256 + t) * 4;       // f32 element offset in 256x32 tile
            const int row = o4 >> 5, kk = o4 & 31;
            const float4 f = *(const float4*)&Ag[(size_t)(row0 + row) * SS + k0 + kk];
            ushort4 u4;
            u4.x = f2bf(f.x); u4.y = f2bf(f.y); u4.z = f2bf(f.z); u4.w = f2bf(f.w);
            *(ushort4*)&As[row * 32 + kk] = u4;
        }
        __syncthreads();
        short8 af[4], bfr[4];
#pragma unroll
        for (int m = 0; m < 4; ++m)
            af[m] = *(const short8*)&As[(wr * 64 + m * 16 + lr) * 32 + half * 8];
#pragma unroll
        for (int n = 0; n < 4; ++n)
            bfr[n] = *(const short8*)&Bs[(n * 16 + lr) * 32 + half * 8];
#pragma unroll
        for (int m = 0; m < 4; ++m)
#pragma unroll
            for (int n = 0; n < 4; ++n)
                acc[m][n] = __builtin_amdgcn_mfma_f32_16x16x32_bf16(af[m], bfr[n], acc[m][n], 0, 0, 0);
        __syncthreads();
    }

#pragma unroll
    for (int m = 0; m < 4; ++m) {
#pragma unroll
        for (int n = 0; n < 4; ++n) {
            const int d = n * 16 + lr;
#pragma unroll
            for (int j = 0; j < 4; ++j) {
                const int r = row0 + wr * 64 + m * 16 + half * 4 + j;
                cb[((size_t)b * SS + r) * DM + h * DK + d] = f2bf(acc[m][n][j]);
            }
        }
    }
}

// ---------------- residual add (bf16 a) + layernorm -> f32 x + bf16 xb -----
__global__ __launch_bounds__(256) void add_ln_kernel(
    const unsigned short* __restrict__ a, const float* __restrict__ xin,
    const float* __restrict__ g, const float* __restrict__ bta,
    float* __restrict__ xout, unsigned short* __restrict__ xbout)
{
    int row = blockIdx.x;
    int t = threadIdx.x;
    const unsigned short* ar = a + (size_t)row * DM;
    const float* xr = xin + (size_t)row * DM;
    float* orow = xout + (size_t)row * DM;
    unsigned short* obr = xbout + (size_t)row * DM;
    __shared__ float red[256];
    float v[3];
    float sum = 0.0f;
#pragma unroll
    for (int i = 0; i < 3; ++i) {
        int c = t + 256 * i;
        v[i] = bf2f(ar[c]) + xr[c];
        sum += v[i];
    }
    red[t] = sum;
    __syncthreads();
    for (int s = 128; s > 0; s >>= 1) {
        if (t < s) red[t] += red[t + s];
        __syncthreads();
    }
    float mean = red[0] * (1.0f / DM);
    __syncthreads();
    float sq = 0.0f;
#pragma unroll
    for (int i = 0; i < 3; ++i) {
        float d = v[i] - mean;
        sq += d * d;
    }
    red[t] = sq;
    __syncthreads();
    for (int s = 128; s > 0; s >>= 1) {
        if (t < s) red[t] += red[t + s];
        __syncthreads();
    }
    float inv = 1.0f / sqrtf(red[0] * (1.0f / DM) + 1e-5f);
#pragma unroll
    for (int i = 0; i < 3; ++i) {
        int c = t + 256 * i;
        float ov = (v[i] - mean) * inv * g[c] + bta[c];
        orow[c] = ov;
        obr[c] = f2bf(ov);
    }
}

extern "C" void kernel_launch(void* const* d_in, const int* in_sizes, int n_in,
                              void* d_out, int out_size, void* d_ws, size_t ws_size,
                              hipStream_t stream)
{
    const int*   toks  = (const int*)d_in[0];
    const int*   amask = (const int*)d_in[1];
    const float* emb   = (const float*)d_in[2];
    const float* pos   = (const float*)d_in[3];
    const float* wq    = (const float*)d_in[4];
    const float* wk    = (const float*)d_in[5];
    const float* wv    = (const float*)d_in[6];
    const float* wo    = (const float*)d_in[7];
    const float* ln1g  = (const float*)d_in[8];
    const float* ln1b  = (const float*)d_in[9];
    const float* w1    = (const float*)d_in[10];
    const float* b1    = (const float*)d_in[11];
    const float* w2    = (const float*)d_in[12];
    const float* b2    = (const float*)d_in[13];
    const float* ln2g  = (const float*)d_in[14];
    const float* ln2b  = (const float*)d_in[15];

    float* out = (float*)d_out;
    char*  wsb = (char*)d_ws;

    const size_t ROWS = (size_t)BB * SS;                 // 4096
    const size_t XSZ  = ROWS * DM;                       // 3,145,728
    const size_t ATTN_L = (size_t)BB * NH * SS * SS;     // 100,663,296

    float*          x   = (float*)(wsb);
    unsigned short* xb  = (unsigned short*)(wsb + 12582912);
    unsigned short* qb  = (unsigned short*)(wsb + 18874368);
    unsigned short* kb_ = (unsigned short*)(wsb + 25165824);
    unsigned short* vt  = (unsigned short*)(wsb + 31457280);
    unsigned short* cb  = (unsigned short*)(wsb + 37748736);
    unsigned short* ffb = (unsigned short*)(wsb + 44040192);
    unsigned short* wt  = (unsigned short*)(wsb + 69206016);

    unsigned short* WQT = wt;
    unsigned short* WKT = wt + 589824;
    unsigned short* WVT = wt + 1179648;
    unsigned short* WOT = wt + 1769472;
    unsigned short* W1T = wt + 2359296;
    unsigned short* W2T = wt + 4718592;

    float* attn_out = out + XSZ;

    embed_kernel<<<ROWS, 256, 0, stream>>>(toks, emb, pos, x, xb);

    for (int l = 0; l < NL; ++l) {
        // per-layer weight transpose+convert (f32 [K][N] -> bf16 [N][K])
        transpose_bf16_kernel<<<dim3(24, 24), 256, 0, stream>>>(wq + (size_t)l * DM * DM, WQT, DM, DM);
        transpose_bf16_kernel<<<dim3(24, 24), 256, 0, stream>>>(wk + (size_t)l * DM * DM, WKT, DM, DM);
        transpose_bf16_kernel<<<dim3(24, 24), 256, 0, stream>>>(wv + (size_t)l * DM * DM, WVT, DM, DM);
        transpose_bf16_kernel<<<dim3(24, 24), 256, 0, stream>>>(wo + (size_t)l * DM * DM, WOT, DM, DM);
        transpose_bf16_kernel<<<dim3(96, 24), 256, 0, stream>>>(w1 + (size_t)l * DM * DFF, W1T, DM, DFF);
        transpose_bf16_kernel<<<dim3(24, 96), 256, 0, stream>>>(w2 + (size_t)l * DFF * DM, W2T, DFF, DM);

        // projections
        gemm_bt<1><<<dim3(6, 32), 256, 0, stream>>>(xb, WQT, nullptr, qb, DM, DM, DM, DM);
        gemm_bt<1><<<dim3(6, 32), 256, 0, stream>>>(xb, WKT, nullptr, kb_, DM, DM, DM, DM);
        gemm_bt<3><<<dim3(6, 32), 256, 0, stream>>>(xb, WVT, nullptr, vt, DM, DM, DM, SS);

        float* attnL = attn_out + (size_t)l * ATTN_L;
        scores_mfma<<<dim3(16, 16, BB * NH), 256, 0, stream>>>(qb, kb_, amask, attnL);
        softmax_kernel<<<BB * NH * SS, 256, 0, stream>>>(attnL);
        ctx_mfma<<<dim3(8, BB * NH), 256, 0, stream>>>(attnL, vt, cb);

        // output projection + LN1
        gemm_bt<1><<<dim3(6, 32), 256, 0, stream>>>(cb, WOT, nullptr, qb, DM, DM, DM, DM);
        add_ln_kernel<<<ROWS, 256, 0, stream>>>(qb, x, ln1g + l * DM, ln1b + l * DM, x, xb);

        // FFN + LN2
        gemm_bt<2><<<dim3(24, 32), 256, 0, stream>>>(xb, W1T, b1 + (size_t)l * DFF, ffb, DM, DM, DM, DFF);
        gemm_bt<1><<<dim3(6, 32), 256, 0, stream>>>(ffb, W2T, b2 + (size_t)l * DM, qb, DFF, DFF, DFF, DM);

        float* xdst = (l == NL - 1) ? out : x;
        add_ln_kernel<<<ROWS, 256, 0, stream>>>(qb, x, ln2g + l * DM, ln2b + l * DM, xdst, xb);
    }
}

// Round 3
// 1030.973 us; speedup vs baseline: 3.4477x; 1.2143x over previous
//
#include <hip/hip_runtime.h>
#include <math.h>

#define DM 768
#define NH 12
#define DK 64
#define DFF 3072
#define BB 2
#define SS 2048
#define NL 2
#define NEGV (-1000000000.0f)

typedef __attribute__((ext_vector_type(8))) short short8;
typedef __attribute__((ext_vector_type(4))) float f32x4;

__device__ inline unsigned short f2bf(float f) {
    unsigned int u = __float_as_uint(f);
    u += 0x7fffu + ((u >> 16) & 1u);
    return (unsigned short)(u >> 16);
}
__device__ inline float bf2f(unsigned short h) {
    return __uint_as_float(((unsigned int)h) << 16);
}

#define GL16(g, l) __builtin_amdgcn_global_load_lds( \
    (const __attribute__((address_space(1))) void*)(g), \
    (__attribute__((address_space(3))) void*)(l), 16, 0, 0)

// ---------------- embed + positional (f32 + bf16 outputs) ----------------
__global__ __launch_bounds__(256) void embed_kernel(
    const int* __restrict__ toks, const float* __restrict__ emb,
    const float* __restrict__ pos, float* __restrict__ x,
    unsigned short* __restrict__ xb)
{
    int rs = blockIdx.x;
    int s = rs & (SS - 1);
    int tok = toks[rs];
    int t = threadIdx.x;
    const float* e = emb + (size_t)tok * DM;
    const float* p = pos + (size_t)s * DM;
    float* xr = x + (size_t)rs * DM;
    unsigned short* xbr = xb + (size_t)rs * DM;
#pragma unroll
    for (int i = 0; i < 3; ++i) {
        int c = t + 256 * i;
        float v = e[c] + p[c];
        xr[c] = v;
        xbr[c] = f2bf(v);
    }
}

// ---------------- weight transpose-convert: W[K][N] f32 -> WT[N][K] bf16 ----
__global__ __launch_bounds__(256) void transpose_bf16_kernel(
    const float* __restrict__ W, unsigned short* __restrict__ WT, int Kd, int Nd)
{
    __shared__ float tile[32][33];
    int n0 = blockIdx.x * 32, k0 = blockIdx.y * 32;
    int c = threadIdx.x & 31, r = threadIdx.x >> 5;   // r in 0..7
#pragma unroll
    for (int i = 0; i < 32; i += 8)
        tile[r + i][c] = W[(size_t)(k0 + r + i) * Nd + n0 + c];
    __syncthreads();
#pragma unroll
    for (int i = 0; i < 32; i += 8)
        WT[(size_t)(n0 + r + i) * Kd + k0 + c] = f2bf(tile[c][r + i]);
}

// ---------------- MFMA GEMM: C[M,N] = A[M,K](bf16) @ Bt[N,K](bf16)^T --------
// 128x128 tile, BK=32, 256 thr = 4 waves (2x2), 4x4 16x16x32 frags per wave.
// OUT_MODE: 0=f32, 1=bf16, 2=bf16+relu, 3=bf16 V-transposed [b][col][s]
template<int OUT_MODE>
__global__ __launch_bounds__(256) void gemm_bt(
    const unsigned short* __restrict__ A, const unsigned short* __restrict__ Bt,
    const float* __restrict__ bias, void* __restrict__ Cv,
    int K, int lda, int ldb, int ldc)
{
    __shared__ unsigned short As[128 * 32];
    __shared__ unsigned short Bs[128 * 32];
    const int t = threadIdx.x;
    const int row0 = blockIdx.y * 128;
    const int col0 = blockIdx.x * 128;
    const int lane = t & 63, wid = t >> 6;
    const int wr = wid >> 1, wc = wid & 1;
    const int half = lane >> 4, lr = lane & 15;
    f32x4 acc[4][4] = {};

    const int o = t * 16;          // byte offset within a 4KB staging round
    const int srow = o >> 6;       // 0..63
    const int skb = (o & 63) >> 1; // ushort offset within 64B row

    for (int k0 = 0; k0 < K; k0 += 32) {
        GL16(A + (size_t)(row0 + srow) * lda + k0 + skb, (unsigned short*)As + o / 2);
        GL16(A + (size_t)(row0 + 64 + srow) * lda + k0 + skb, (unsigned short*)As + 2048 + o / 2);
        GL16(Bt + (size_t)(col0 + srow) * ldb + k0 + skb, (unsigned short*)Bs + o / 2);
        GL16(Bt + (size_t)(col0 + 64 + srow) * ldb + k0 + skb, (unsigned short*)Bs + 2048 + o / 2);
        __syncthreads();
        short8 af[4], bfr[4];
#pragma unroll
        for (int m = 0; m < 4; ++m)
            af[m] = *(const short8*)&As[(wr * 64 + m * 16 + lr) * 32 + half * 8];
#pragma unroll
        for (int n = 0; n < 4; ++n)
            bfr[n] = *(const short8*)&Bs[(wc * 64 + n * 16 + lr) * 32 + half * 8];
#pragma unroll
        for (int m = 0; m < 4; ++m)
#pragma unroll
            for (int n = 0; n < 4; ++n)
                acc[m][n] = __builtin_amdgcn_mfma_f32_16x16x32_bf16(af[m], bfr[n], acc[m][n], 0, 0, 0);
        __syncthreads();
    }

#pragma unroll
    for (int m = 0; m < 4; ++m) {
#pragma unroll
        for (int n = 0; n < 4; ++n) {
            const int cidx = col0 + wc * 64 + n * 16 + lr;
            const float bv = bias ? bias[cidx] : 0.0f;
#pragma unroll
            for (int j = 0; j < 4; ++j) {
                const int r = row0 + wr * 64 + m * 16 + half * 4 + j;
                float v = acc[m][n][j] + bv;
                if (OUT_MODE == 2) v = fmaxf(v, 0.0f);
                if (OUT_MODE == 0) {
                    ((float*)Cv)[(size_t)r * ldc + cidx] = v;
                } else if (OUT_MODE == 3) {
                    int b = r >> 11, s = r & 2047;
                    ((unsigned short*)Cv)[((size_t)b * DM + cidx) * SS + s] = f2bf(v);
                } else {
                    ((unsigned short*)Cv)[(size_t)r * ldc + cidx] = f2bf(v);
                }
            }
        }
    }
}

// ---------------- fused attention: scores + softmax + PV --------------------
// Block: one (b,h) x 16 q-rows, 256 threads (4 waves).
// E = exp(scaled masked scores) kept in 64KB LDS strip (bf16, XOR-swizzled);
// P written once (f32) to d_out, ctx written bf16 for Wo GEMM.
// No-max softmax: scores are small (|s|<~3), exp in f32 is exact enough;
// masked -> 0 (== exp(-1e9)), matching reference semantics.
__global__ __launch_bounds__(256) void attn_fused(
    const unsigned short* __restrict__ qg, const unsigned short* __restrict__ kg,
    const unsigned short* __restrict__ vt, const int* __restrict__ amask,
    float* __restrict__ attnL, unsigned short* __restrict__ cb)
{
    __shared__ unsigned short Ks[128 * 64];   // 16KB [krow][dk], 16B chunks swizzled c^=(row&7)
    __shared__ unsigned short Vs[64 * 128];   // 16KB [d][s], swizzled
    __shared__ unsigned short Es[16 * 2048];  // 64KB [qrow][kcol], swizzled
    __shared__ float redsum[4][16];
    __shared__ float invs[16];

    const int t = threadIdx.x;
    const int bh = blockIdx.y, b = bh / NH, h = bh % NH;
    const int q0 = blockIdx.x * 16;
    const int lane = t & 63, w = t >> 6;
    const int half = lane >> 4, lr = lane & 15;   // half in 0..3
    const int* am = amask + b * SS;

    // Q A-fragments: row = lr, k = ks*32 + half*8
    const unsigned short* qrow = qg + ((size_t)b * SS + q0 + lr) * DM + h * DK + half * 8;
    short8 afq[2];
    afq[0] = *(const short8*)(qrow);
    afq[1] = *(const short8*)(qrow + 32);

    f32x4 ctxa0 = {}, ctxa1 = {};   // PV acc (split to break dep chain)
    float vsum[4] = {};

    for (int kt = 0; kt < 16; ++kt) {
        // ---- stage K tile (128x64) and V^T tile (64x128), pre-swizzled src
        {
            const unsigned short* Kg = kg + ((size_t)b * SS + kt * 128) * DM + h * DK;
#pragma unroll
            for (int r = 0; r < 4; ++r) {
                int o = r * 4096 + t * 16;
                int krow = o >> 7;
                int cp = (o >> 4) & 7;
                GL16(Kg + (size_t)krow * DM + ((cp ^ (krow & 7)) << 3), (char*)Ks + o);
            }
            const unsigned short* Vg = vt + ((size_t)b * DM + h * DK) * SS + kt * 128;
#pragma unroll
            for (int r = 0; r < 4; ++r) {
                int o = r * 4096 + t * 16;
                int d = o >> 8;
                int cp = (o >> 4) & 15;
                GL16(Vg + (size_t)d * SS + ((cp ^ (d & 7)) << 3), (char*)Vs + o);
            }
        }
        __syncthreads();

        // ---- QK^T (2 n-frags per wave) + exp + E-store
#pragma unroll
        for (int nn = 0; nn < 2; ++nn) {
            const int ng = w * 2 + nn;
            const int krl = ng * 16 + lr;        // local k-col 0..127
            f32x4 s = {};
#pragma unroll
            for (int ks = 0; ks < 2; ++ks) {
                int c = ks * 4 + half;           // chunk 0..7 within 128B K row
                short8 bk = *(const short8*)((const char*)Ks + krl * 128 + ((c ^ (krl & 7)) << 4));
                s = __builtin_amdgcn_mfma_f32_16x16x32_bf16(afq[ks], bk, s, 0, 0, 0);
            }
            const int kpos = kt * 128 + krl;
            const bool pad = (am[kpos] == 0);
#pragma unroll
            for (int j = 0; j < 4; ++j) {
                int row = half * 4 + j;
                int qpos = q0 + row;
                bool keep = pad || (kpos > qpos);  // FAITHFUL to reference mask
                float e = keep ? __expf(0.125f * s[j]) : 0.0f;
                vsum[j] += e;
                *((unsigned short*)((char*)Es + row * 4096 + ((kpos * 2) ^ ((row & 7) << 4)))) = f2bf(e);
            }
        }
        __syncthreads();

        // ---- PV: ctx += E[16 x 128] @ V[128 x 64], wave w owns d-block w
#pragma unroll
        for (int ks = 0; ks < 4; ++ks) {
            const int dl = w * 16 + lr;
            const int cv = ks * 4 + half;        // chunk 0..15 within 256B V row
            short8 bv = *(const short8*)((const char*)Vs + dl * 256 + ((cv ^ (dl & 7)) << 4));
            const int colb = (kt * 128 + ks * 32 + half * 8) * 2;
            short8 ae = *(const short8*)((const char*)Es + lr * 4096 + (colb ^ ((lr & 7) << 4)));
            if (ks & 1)
                ctxa1 = __builtin_amdgcn_mfma_f32_16x16x32_bf16(ae, bv, ctxa1, 0, 0, 0);
            else
                ctxa0 = __builtin_amdgcn_mfma_f32_16x16x32_bf16(ae, bv, ctxa0, 0, 0, 0);
        }
        __syncthreads();
    }

    // ---- row sums: reduce over lr lanes, then across waves
#pragma unroll
    for (int j = 0; j < 4; ++j) {
        vsum[j] += __shfl_xor(vsum[j], 1, 64);
        vsum[j] += __shfl_xor(vsum[j], 2, 64);
        vsum[j] += __shfl_xor(vsum[j], 4, 64);
        vsum[j] += __shfl_xor(vsum[j], 8, 64);
    }
    if (lr == 0) {
#pragma unroll
        for (int j = 0; j < 4; ++j) redsum[w][half * 4 + j] = vsum[j];
    }
    __syncthreads();
    if (t < 16) {
        float rs = redsum[0][t] + redsum[1][t] + redsum[2][t] + redsum[3][t];
        invs[t] = (rs > 0.0f) ? 1.0f / rs : 0.0f;
    }
    __syncthreads();

    // ---- write P = E * inv (f32), 16 rows x 2048 cols
    float* ab = attnL + ((size_t)bh * SS + q0) * SS;
#pragma unroll
    for (int i = 0; i < 8; ++i) {
        int task = i * 256 + t;
        int row = task >> 7;
        int cl = task & 127;
        short8 ev = *(const short8*)((const char*)Es + row * 4096 + ((cl << 4) ^ ((row & 7) << 4)));
        float inv = invs[row];
        float* dst = ab + (size_t)row * SS + cl * 8;
        float4 o0, o1;
        o0.x = bf2f((unsigned short)ev[0]) * inv;
        o0.y = bf2f((unsigned short)ev[1]) * inv;
        o0.z = bf2f((unsigned short)ev[2]) * inv;
        o0.w = bf2f((unsigned short)ev[3]) * inv;
        o1.x = bf2f((unsigned short)ev[4]) * inv;
        o1.y = bf2f((unsigned short)ev[5]) * inv;
        o1.z = bf2f((unsigned short)ev[6]) * inv;
        o1.w = bf2f((unsigned short)ev[7]) * inv;
        *(float4*)(dst) = o0;
        *(float4*)(dst + 4) = o1;
    }

    // ---- write ctx (bf16): col d = w*16+lr, rows half*4+j
#pragma unroll
    for (int j = 0; j < 4; ++j) {
        int row = half * 4 + j;
        float v = (ctxa0[j] + ctxa1[j]) * invs[row];
        cb[((size_t)b * SS + q0 + row) * DM + h * DK + w * 16 + lr] = f2bf(v);
    }
}

// ---------------- residual add (bf16 a) + layernorm -> f32 x + bf16 xb -----
__global__ __launch_bounds__(256) void add_ln_kernel(
    const unsigned short* __restrict__ a, const float* __restrict__ xin,
    const float* __restrict__ g, const float* __restrict__ bta,
    float* __restrict__ xout, unsigned short* __restrict__ xbout)
{
    int row = blockIdx.x;
    int t = threadIdx.x;
    const unsigned short* ar = a + (size_t)row * DM;
    const float* xr = xin + (size_t)row * DM;
    float* orow = xout + (size_t)row * DM;
    unsigned short* obr = xbout + (size_t)row * DM;
    __shared__ float red[256];
    float v[3];
    float sum = 0.0f;
#pragma unroll
    for (int i = 0; i < 3; ++i) {
        int c = t + 256 * i;
        v[i] = bf2f(ar[c]) + xr[c];
        sum += v[i];
    }
    red[t] = sum;
    __syncthreads();
    for (int s = 128; s > 0; s >>= 1) {
        if (t < s) red[t] += red[t + s];
        __syncthreads();
    }
    float mean = red[0] * (1.0f / DM);
    __syncthreads();
    float sq = 0.0f;
#pragma unroll
    for (int i = 0; i < 3; ++i) {
        float d = v[i] - mean;
        sq += d * d;
    }
    red[t] = sq;
    __syncthreads();
    for (int s = 128; s > 0; s >>= 1) {
        if (t < s) red[t] += red[t + s];
        __syncthreads();
    }
    float inv = 1.0f / sqrtf(red[0] * (1.0f / DM) + 1e-5f);
#pragma unroll
    for (int i = 0; i < 3; ++i) {
        int c = t + 256 * i;
        float ov = (v[i] - mean) * inv * g[c] + bta[c];
        orow[c] = ov;
        obr[c] = f2bf(ov);
    }
}

extern "C" void kernel_launch(void* const* d_in, const int* in_sizes, int n_in,
                              void* d_out, int out_size, void* d_ws, size_t ws_size,
                              hipStream_t stream)
{
    const int*   toks  = (const int*)d_in[0];
    const int*   amask = (const int*)d_in[1];
    const float* emb   = (const float*)d_in[2];
    const float* pos   = (const float*)d_in[3];
    const float* wq    = (const float*)d_in[4];
    const float* wk    = (const float*)d_in[5];
    const float* wv    = (const float*)d_in[6];
    const float* wo    = (const float*)d_in[7];
    const float* ln1g  = (const float*)d_in[8];
    const float* ln1b  = (const float*)d_in[9];
    const float* w1    = (const float*)d_in[10];
    const float* b1    = (const float*)d_in[11];
    const float* w2    = (const float*)d_in[12];
    const float* b2    = (const float*)d_in[13];
    const float* ln2g  = (const float*)d_in[14];
    const float* ln2b  = (const float*)d_in[15];

    float* out = (float*)d_out;
    char*  wsb = (char*)d_ws;

    const size_t ROWS = (size_t)BB * SS;                 // 4096
    const size_t XSZ  = ROWS * DM;                       // 3,145,728
    const size_t ATTN_L = (size_t)BB * NH * SS * SS;     // 100,663,296

    float*          x   = (float*)(wsb);
    unsigned short* xb  = (unsigned short*)(wsb + 12582912);
    unsigned short* qb  = (unsigned short*)(wsb + 18874368);
    unsigned short* kb_ = (unsigned short*)(wsb + 25165824);
    unsigned short* vt  = (unsigned short*)(wsb + 31457280);
    unsigned short* cb  = (unsigned short*)(wsb + 37748736);
    unsigned short* ffb = (unsigned short*)(wsb + 44040192);
    unsigned short* wt  = (unsigned short*)(wsb + 69206016);

    unsigned short* WQT = wt;
    unsigned short* WKT = wt + 589824;
    unsigned short* WVT = wt + 1179648;
    unsigned short* WOT = wt + 1769472;
    unsigned short* W1T = wt + 2359296;
    unsigned short* W2T = wt + 4718592;

    float* attn_out = out + XSZ;

    embed_kernel<<<ROWS, 256, 0, stream>>>(toks, emb, pos, x, xb);

    for (int l = 0; l < NL; ++l) {
        // per-layer weight transpose+convert (f32 [K][N] -> bf16 [N][K])
        transpose_bf16_kernel<<<dim3(24, 24), 256, 0, stream>>>(wq + (size_t)l * DM * DM, WQT, DM, DM);
        transpose_bf16_kernel<<<dim3(24, 24), 256, 0, stream>>>(wk + (size_t)l * DM * DM, WKT, DM, DM);
        transpose_bf16_kernel<<<dim3(24, 24), 256, 0, stream>>>(wv + (size_t)l * DM * DM, WVT, DM, DM);
        transpose_bf16_kernel<<<dim3(24, 24), 256, 0, stream>>>(wo + (size_t)l * DM * DM, WOT, DM, DM);
        transpose_bf16_kernel<<<dim3(96, 24), 256, 0, stream>>>(w1 + (size_t)l * DM * DFF, W1T, DM, DFF);
        transpose_bf16_kernel<<<dim3(24, 96), 256, 0, stream>>>(w2 + (size_t)l * DFF * DM, W2T, DFF, DM);

        // projections
        gemm_bt<1><<<dim3(6, 32), 256, 0, stream>>>(xb, WQT, nullptr, qb, DM, DM, DM, DM);
        gemm_bt<1><<<dim3(6, 32), 256, 0, stream>>>(xb, WKT, nullptr, kb_, DM, DM, DM, DM);
        gemm_bt<3><<<dim3(6, 32), 256, 0, stream>>>(xb, WVT, nullptr, vt, DM, DM, DM, SS);

        float* attnL = attn_out + (size_t)l * ATTN_L;
        attn_fused<<<dim3(SS / 16, BB * NH), 256, 0, stream>>>(qb, kb_, vt, amask, attnL, cb);

        // output projection + LN1
        gemm_bt<1><<<dim3(6, 32), 256, 0, stream>>>(cb, WOT, nullptr, qb, DM, DM, DM, DM);
        add_ln_kernel<<<ROWS, 256, 0, stream>>>(qb, x, ln1g + l * DM, ln1b + l * DM, x, xb);

        // FFN + LN2
        gemm_bt<2><<<dim3(24, 32), 256, 0, stream>>>(xb, W1T, b1 + (size_t)l * DFF, ffb, DM, DM, DM, DFF);
        gemm_bt<1><<<dim3(6, 32), 256, 0, stream>>>(ffb, W2T, b2 + (size_t)l * DM, qb, DFF, DFF, DFF, DM);

        float* xdst = (l == NL - 1) ? out : x;
        add_ln_kernel<<<ROWS, 256, 0, stream>>>(qb, x, ln2g + l * DM, ln2b + l * DM, xdst, xb);
    }
}

// Round 5
// 924.223 us; speedup vs baseline: 3.8459x; 1.1155x over previous
//
#include <hip/hip_runtime.h>
#include <math.h>

#define DM 768
#define NH 12
#define DK 64
#define DFF 3072
#define BB 2
#define SS 2048
#define NL 2

typedef __attribute__((ext_vector_type(8))) short short8;
typedef __attribute__((ext_vector_type(4))) float f32x4;

__device__ inline unsigned short f2bf(float f) {
    unsigned int u = __float_as_uint(f);
    u += 0x7fffu + ((u >> 16) & 1u);
    return (unsigned short)(u >> 16);
}
__device__ inline float bf2f(unsigned short h) {
    return __uint_as_float(((unsigned int)h) << 16);
}

#define GL16(g, l) __builtin_amdgcn_global_load_lds( \
    (const __attribute__((address_space(1))) void*)(g), \
    (__attribute__((address_space(3))) void*)(l), 16, 0, 0)

// ---------------- embed + positional (f32 + bf16 outputs) ----------------
__global__ __launch_bounds__(256) void embed_kernel(
    const int* __restrict__ toks, const float* __restrict__ emb,
    const float* __restrict__ pos, float* __restrict__ x,
    unsigned short* __restrict__ xb)
{
    int rs = blockIdx.x;
    int s = rs & (SS - 1);
    int tok = toks[rs];
    int t = threadIdx.x;
    const float* e = emb + (size_t)tok * DM;
    const float* p = pos + (size_t)s * DM;
    float* xr = x + (size_t)rs * DM;
    unsigned short* xbr = xb + (size_t)rs * DM;
#pragma unroll
    for (int i = 0; i < 3; ++i) {
        int c = t + 256 * i;
        float v = e[c] + p[c];
        xr[c] = v;
        xbr[c] = f2bf(v);
    }
}

// ---------------- batched weight transpose-convert (one launch per layer) ---
// 6912 tiles: wq(576) wk(576) wv(576) wo(576) w1(2304) w2(2304)
// dst layout in wt (bf16): QKVT[2304][768] | WOT[768][768] | W1T[3072][768] | W2T[768][3072]
__global__ __launch_bounds__(256) void prep_weights(
    const float* __restrict__ wq, const float* __restrict__ wk,
    const float* __restrict__ wv, const float* __restrict__ wo,
    const float* __restrict__ w1, const float* __restrict__ w2,
    unsigned short* __restrict__ wt)
{
    __shared__ float tile[32][33];
    int id = blockIdx.x;
    const float* src; unsigned short* dst; int Kd, Nd, nt, kt;
    if (id < 2304) {
        int m = id / 576, r = id % 576;
        src = (m == 0) ? wq : (m == 1) ? wk : (m == 2) ? wv : wo;
        dst = wt + (size_t)m * 589824;   // m=3 (wo) lands at 1769472 ✓
        Kd = 768; Nd = 768; nt = r / 24; kt = r % 24;
    } else if (id < 4608) {
        int r = id - 2304;
        src = w1; dst = wt + 2359296; Kd = 768; Nd = 3072;
        nt = r / 24; kt = r % 24;
    } else {
        int r = id - 4608;
        src = w2; dst = wt + 4718592; Kd = 3072; Nd = 768;
        nt = r / 96; kt = r % 96;
    }
    int n0 = nt * 32, k0 = kt * 32;
    int c = threadIdx.x & 31, rr = threadIdx.x >> 5;
#pragma unroll
    for (int i = 0; i < 32; i += 8)
        tile[rr + i][c] = src[(size_t)(k0 + rr + i) * Nd + n0 + c];
    __syncthreads();
#pragma unroll
    for (int i = 0; i < 32; i += 8)
        dst[(size_t)(n0 + rr + i) * Kd + k0 + c] = f2bf(tile[c][rr + i]);
}

// ---------------- V transpose: vb[b*S+s][DM] bf16 -> vt[b][DM][S] bf16 ------
__global__ __launch_bounds__(256) void transpose_v(
    const unsigned short* __restrict__ vb, unsigned short* __restrict__ vt)
{
    __shared__ unsigned short tile[32][33];
    int c0 = blockIdx.x * 32;
    int r0 = blockIdx.y * 32;
    int c = threadIdx.x & 31, rr = threadIdx.x >> 5;
#pragma unroll
    for (int i = 0; i < 32; i += 8)
        tile[rr + i][c] = vb[(size_t)(r0 + rr + i) * DM + c0 + c];
    __syncthreads();
    int b = r0 >> 11;
    int s0 = r0 & 2047;
#pragma unroll
    for (int i = 0; i < 32; i += 8)
        vt[((size_t)b * DM + c0 + rr + i) * SS + s0 + c] = tile[c][rr + i];
}

// ---------------- MFMA GEMM: C[M,N] = A[M,K](bf16) @ Bt[N,K](bf16)^T --------
// 128x128 tile, BK=32, 256 thr = 4 waves (2x2), 4x4 16x16x32 frags per wave.
// OUT_MODE: 1=bf16, 2=bf16+relu, 4=bf16 into 3 consecutive [4096][768] mats
template<int OUT_MODE>
__global__ __launch_bounds__(256) void gemm_bt(
    const unsigned short* __restrict__ A, const unsigned short* __restrict__ Bt,
    const float* __restrict__ bias, void* __restrict__ Cv,
    int K, int lda, int ldb, int ldc)
{
    __shared__ unsigned short As[128 * 32];
    __shared__ unsigned short Bs[128 * 32];
    const int t = threadIdx.x;
    const int row0 = blockIdx.y * 128;
    const int col0 = blockIdx.x * 128;
    const int lane = t & 63, wid = t >> 6;
    const int wr = wid >> 1, wc = wid & 1;
    const int half = lane >> 4, lr = lane & 15;
    f32x4 acc[4][4] = {};

    const int o = t * 16;
    const int srow = o >> 6;
    const int skb = (o & 63) >> 1;

    for (int k0 = 0; k0 < K; k0 += 32) {
        GL16(A + (size_t)(row0 + srow) * lda + k0 + skb, (unsigned short*)As + o / 2);
        GL16(A + (size_t)(row0 + 64 + srow) * lda + k0 + skb, (unsigned short*)As + 2048 + o / 2);
        GL16(Bt + (size_t)(col0 + srow) * ldb + k0 + skb, (unsigned short*)Bs + o / 2);
        GL16(Bt + (size_t)(col0 + 64 + srow) * ldb + k0 + skb, (unsigned short*)Bs + 2048 + o / 2);
        __syncthreads();
        short8 af[4], bfr[4];
#pragma unroll
        for (int m = 0; m < 4; ++m)
            af[m] = *(const short8*)&As[(wr * 64 + m * 16 + lr) * 32 + half * 8];
#pragma unroll
        for (int n = 0; n < 4; ++n)
            bfr[n] = *(const short8*)&Bs[(wc * 64 + n * 16 + lr) * 32 + half * 8];
#pragma unroll
        for (int m = 0; m < 4; ++m)
#pragma unroll
            for (int n = 0; n < 4; ++n)
                acc[m][n] = __builtin_amdgcn_mfma_f32_16x16x32_bf16(af[m], bfr[n], acc[m][n], 0, 0, 0);
        __syncthreads();
    }

#pragma unroll
    for (int m = 0; m < 4; ++m) {
#pragma unroll
        for (int n = 0; n < 4; ++n) {
            const int cidx = col0 + wc * 64 + n * 16 + lr;
            const float bv = bias ? bias[cidx] : 0.0f;
#pragma unroll
            for (int j = 0; j < 4; ++j) {
                const int r = row0 + wr * 64 + m * 16 + half * 4 + j;
                float v = acc[m][n][j] + bv;
                if (OUT_MODE == 2) v = fmaxf(v, 0.0f);
                if (OUT_MODE == 4) {
                    int mi = (cidx >= 1536) ? 2 : (cidx >= 768 ? 1 : 0);
                    int cl = cidx - mi * 768;
                    ((unsigned short*)Cv)[((size_t)mi * 4096 + r) * 768 + cl] = f2bf(v);
                } else {
                    ((unsigned short*)Cv)[(size_t)r * ldc + cidx] = f2bf(v);
                }
            }
        }
    }
}

// ---------------- fused attention v2: 2-pass, dbuf, 72KB LDS ---------------
// Block: one (b,h) x 16 q-rows, 256 threads (4 waves).
// Pass A: row-sums of exp(masked scaled scores). Pass B: normalized E ->
// P-write (nontemporal) + PV MFMA via 4KB dbuf E-tile.
__global__ __launch_bounds__(256) void attn_fused(
    const unsigned short* __restrict__ qg, const unsigned short* __restrict__ kg,
    const unsigned short* __restrict__ vt, const int* __restrict__ amask,
    float* __restrict__ attnL, unsigned short* __restrict__ cb)
{
    __shared__ unsigned short Ks[2][128 * 64];   // 2x16KB, swizzled
    __shared__ unsigned short Vs[2][64 * 128];   // 2x16KB, swizzled
    __shared__ unsigned short Et[2][16 * 128];   // 2x4KB, swizzled
    __shared__ float redsum[4][16];
    __shared__ float invs[16];

    const int t = threadIdx.x;
    const int bh = blockIdx.y, b = bh / NH, h = bh % NH;
    const int q0 = blockIdx.x * 16;
    const int lane = t & 63, w = t >> 6;
    const int half = lane >> 4, lr = lane & 15;
    const int* am = amask + b * SS;

    const unsigned short* qrow = qg + ((size_t)b * SS + q0 + lr) * DM + h * DK + half * 8;
    const short8 afq0 = *(const short8*)(qrow);
    const short8 afq1 = *(const short8*)(qrow + 32);

    const unsigned short* Kg = kg + (size_t)b * SS * DM + h * DK;
    const unsigned short* Vg = vt + ((size_t)b * DM + h * DK) * SS;

#define STAGE_K(kt, buf) { \
    _Pragma("unroll") \
    for (int r_ = 0; r_ < 4; ++r_) { \
        int o_ = r_ * 4096 + t * 16; \
        int krow_ = o_ >> 7; \
        int cp_ = (o_ >> 4) & 7; \
        GL16(Kg + (size_t)((kt) * 128 + krow_) * DM + ((cp_ ^ (krow_ & 7)) << 3), (char*)Ks[buf] + o_); \
    } }
#define STAGE_V(kt, buf) { \
    _Pragma("unroll") \
    for (int r_ = 0; r_ < 4; ++r_) { \
        int o_ = r_ * 4096 + t * 16; \
        int d_ = o_ >> 8; \
        int cp_ = (o_ >> 4) & 15; \
        GL16(Vg + (size_t)d_ * SS + (kt) * 128 + ((cp_ ^ (d_ & 7)) << 3), (char*)Vs[buf] + o_); \
    } }

    // ================= pass A: row sums =================
    float vsum[4] = {};
    STAGE_K(0, 0);
    for (int kt = 0; kt < 16; ++kt) {
        asm volatile("s_waitcnt vmcnt(0)" ::: "memory");
        __builtin_amdgcn_s_barrier();
        if (kt < 15) STAGE_K(kt + 1, (kt + 1) & 1);
        const char* kbuf = (const char*)Ks[kt & 1];
#pragma unroll
        for (int nn = 0; nn < 2; ++nn) {
            const int krl = (w * 2 + nn) * 16 + lr;
            f32x4 s = {};
            short8 bk0 = *(const short8*)(kbuf + krl * 128 + ((half ^ (krl & 7)) << 4));
            s = __builtin_amdgcn_mfma_f32_16x16x32_bf16(afq0, bk0, s, 0, 0, 0);
            short8 bk1 = *(const short8*)(kbuf + krl * 128 + (((4 + half) ^ (krl & 7)) << 4));
            s = __builtin_amdgcn_mfma_f32_16x16x32_bf16(afq1, bk1, s, 0, 0, 0);
            const int kpos = kt * 128 + krl;
            const bool pad = (am[kpos] == 0);
#pragma unroll
            for (int j = 0; j < 4; ++j) {
                int qpos = q0 + half * 4 + j;
                if (pad || (kpos > qpos))      // FAITHFUL: keep where pad||future
                    vsum[j] += __expf(0.125f * s[j]);
            }
        }
    }
    __syncthreads();

#pragma unroll
    for (int j = 0; j < 4; ++j) {
        vsum[j] += __shfl_xor(vsum[j], 1, 64);
        vsum[j] += __shfl_xor(vsum[j], 2, 64);
        vsum[j] += __shfl_xor(vsum[j], 4, 64);
        vsum[j] += __shfl_xor(vsum[j], 8, 64);
    }
    if (lr == 0) {
#pragma unroll
        for (int j = 0; j < 4; ++j) redsum[w][half * 4 + j] = vsum[j];
    }
    __syncthreads();
    if (t < 16) {
        float rs = redsum[0][t] + redsum[1][t] + redsum[2][t] + redsum[3][t];
        invs[t] = (rs > 0.0f) ? 1.0f / rs : 0.0f;
    }
    __syncthreads();

    // ================= pass B: normalized E -> P + PV =================
    f32x4 ctxa0 = {}, ctxa1 = {};
    float* ab = attnL + ((size_t)bh * SS + q0) * SS;
    const int prow = t >> 4, pchunk = t & 15;    // P cooperative write mapping
    STAGE_K(0, 0);
    STAGE_V(0, 0);
    for (int kt = 0; kt < 16; ++kt) {
        if (kt == 0) {
            asm volatile("s_waitcnt vmcnt(0)" ::: "memory");
        } else {
            asm volatile("s_waitcnt vmcnt(2)" ::: "memory");  // 8 loads done, ≤2 P-stores in flight
        }
        __builtin_amdgcn_s_barrier();
        if (kt < 15) { STAGE_K(kt + 1, (kt + 1) & 1); STAGE_V(kt + 1, (kt + 1) & 1); }
        const char* kbuf = (const char*)Ks[kt & 1];
        char* ebuf = (char*)Et[kt & 1];
#pragma unroll
        for (int nn = 0; nn < 2; ++nn) {
            const int krl = (w * 2 + nn) * 16 + lr;
            f32x4 s = {};
            short8 bk0 = *(const short8*)(kbuf + krl * 128 + ((half ^ (krl & 7)) << 4));
            s = __builtin_amdgcn_mfma_f32_16x16x32_bf16(afq0, bk0, s, 0, 0, 0);
            short8 bk1 = *(const short8*)(kbuf + krl * 128 + (((4 + half) ^ (krl & 7)) << 4));
            s = __builtin_amdgcn_mfma_f32_16x16x32_bf16(afq1, bk1, s, 0, 0, 0);
            const int kpos = kt * 128 + krl;
            const bool pad = (am[kpos] == 0);
#pragma unroll
            for (int j = 0; j < 4; ++j) {
                int row = half * 4 + j;
                int qpos = q0 + row;
                bool keep = pad || (kpos > qpos);
                float e = keep ? __expf(0.125f * s[j]) * invs[row] : 0.0f;
                *((unsigned short*)(ebuf + row * 256 + ((krl * 2) ^ ((row & 7) << 4)))) = f2bf(e);
            }
        }
        asm volatile("s_waitcnt lgkmcnt(0)" ::: "memory");   // E-writes visible
        __builtin_amdgcn_s_barrier();

        // PV: ctx += E[16x128] @ V[128x64]; wave w owns d-cols w*16..w*16+15
        const char* vbuf = (const char*)Vs[kt & 1];
#pragma unroll
        for (int ks = 0; ks < 4; ++ks) {
            const int dl = w * 16 + lr;
            const int cv = ks * 4 + half;
            short8 bv = *(const short8*)(vbuf + dl * 256 + ((cv ^ (dl & 7)) << 4));
            short8 ae = *(const short8*)(ebuf + lr * 256 + ((ks * 64 + half * 16) ^ ((lr & 7) << 4)));
            if (ks & 1)
                ctxa1 = __builtin_amdgcn_mfma_f32_16x16x32_bf16(ae, bv, ctxa1, 0, 0, 0);
            else
                ctxa0 = __builtin_amdgcn_mfma_f32_16x16x32_bf16(ae, bv, ctxa0, 0, 0, 0);
        }

        // P-write: 256 threads cover 16 rows x 16 chunks (8 f32 each), nontemporal
        {
            short8 ev = *(const short8*)(ebuf + prow * 256 + ((pchunk << 4) ^ ((prow & 7) << 4)));
            float* dst = ab + (size_t)prow * SS + kt * 128 + pchunk * 8;
            f32x4 o0, o1;
            o0[0] = bf2f((unsigned short)ev[0]); o0[1] = bf2f((unsigned short)ev[1]);
            o0[2] = bf2f((unsigned short)ev[2]); o0[3] = bf2f((unsigned short)ev[3]);
            o1[0] = bf2f((unsigned short)ev[4]); o1[1] = bf2f((unsigned short)ev[5]);
            o1[2] = bf2f((unsigned short)ev[6]); o1[3] = bf2f((unsigned short)ev[7]);
            __builtin_nontemporal_store(o0, (f32x4*)dst);
            __builtin_nontemporal_store(o1, (f32x4*)(dst + 4));
        }
    }

    // ctx write (already normalized)
#pragma unroll
    for (int j = 0; j < 4; ++j) {
        int row = half * 4 + j;
        cb[((size_t)b * SS + q0 + row) * DM + h * DK + w * 16 + lr] = f2bf(ctxa0[j] + ctxa1[j]);
    }
#undef STAGE_K
#undef STAGE_V
}

// ---------------- residual add (bf16 a) + layernorm -> f32 x + bf16 xb -----
__global__ __launch_bounds__(256) void add_ln_kernel(
    const unsigned short* __restrict__ a, const float* __restrict__ xin,
    const float* __restrict__ g, const float* __restrict__ bta,
    float* __restrict__ xout, unsigned short* __restrict__ xbout)
{
    int row = blockIdx.x;
    int t = threadIdx.x;
    const unsigned short* ar = a + (size_t)row * DM;
    const float* xr = xin + (size_t)row * DM;
    float* orow = xout + (size_t)row * DM;
    unsigned short* obr = xbout + (size_t)row * DM;
    __shared__ float red[256];
    float v[3];
    float sum = 0.0f;
#pragma unroll
    for (int i = 0; i < 3; ++i) {
        int c = t + 256 * i;
        v[i] = bf2f(ar[c]) + xr[c];
        sum += v[i];
    }
    red[t] = sum;
    __syncthreads();
    for (int s = 128; s > 0; s >>= 1) {
        if (t < s) red[t] += red[t + s];
        __syncthreads();
    }
    float mean = red[0] * (1.0f / DM);
    __syncthreads();
    float sq = 0.0f;
#pragma unroll
    for (int i = 0; i < 3; ++i) {
        float d = v[i] - mean;
        sq += d * d;
    }
    red[t] = sq;
    __syncthreads();
    for (int s = 128; s > 0; s >>= 1) {
        if (t < s) red[t] += red[t + s];
        __syncthreads();
    }
    float inv = 1.0f / sqrtf(red[0] * (1.0f / DM) + 1e-5f);
#pragma unroll
    for (int i = 0; i < 3; ++i) {
        int c = t + 256 * i;
        float ov = (v[i] - mean) * inv * g[c] + bta[c];
        orow[c] = ov;
        obr[c] = f2bf(ov);
    }
}

extern "C" void kernel_launch(void* const* d_in, const int* in_sizes, int n_in,
                              void* d_out, int out_size, void* d_ws, size_t ws_size,
                              hipStream_t stream)
{
    const int*   toks  = (const int*)d_in[0];
    const int*   amask = (const int*)d_in[1];
    const float* emb   = (const float*)d_in[2];
    const float* pos   = (const float*)d_in[3];
    const float* wq    = (const float*)d_in[4];
    const float* wk    = (const float*)d_in[5];
    const float* wv    = (const float*)d_in[6];
    const float* wo    = (const float*)d_in[7];
    const float* ln1g  = (const float*)d_in[8];
    const float* ln1b  = (const float*)d_in[9];
    const float* w1    = (const float*)d_in[10];
    const float* b1    = (const float*)d_in[11];
    const float* w2    = (const float*)d_in[12];
    const float* b2    = (const float*)d_in[13];
    const float* ln2g  = (const float*)d_in[14];
    const float* ln2b  = (const float*)d_in[15];

    float* out = (float*)d_out;
    char*  wsb = (char*)d_ws;

    const size_t ROWS = (size_t)BB * SS;                 // 4096
    const size_t XSZ  = ROWS * DM;                       // 3,145,728
    const size_t ATTN_L = (size_t)BB * NH * SS * SS;     // 100,663,296

    float*          x    = (float*)(wsb);                          // 12.58 MB
    unsigned short* xb   = (unsigned short*)(wsb + 12582912);      // 6.29 MB
    unsigned short* qb   = (unsigned short*)(wsb + 18874368);      // 6.29 MB (QKV out 0)
    unsigned short* kbuf = (unsigned short*)(wsb + 25165824);      // 6.29 MB (QKV out 1)
    unsigned short* vb   = (unsigned short*)(wsb + 31457280);      // 6.29 MB (QKV out 2)
    unsigned short* cb   = (unsigned short*)(wsb + 37748736);      // 6.29 MB
    unsigned short* vt   = (unsigned short*)(wsb + 44040192);      // aliases ffb[0:6.29MB]
    unsigned short* ffb  = (unsigned short*)(wsb + 44040192);      // 25.17 MB
    unsigned short* wt   = (unsigned short*)(wsb + 69206016);      // 14.16 MB (per-layer)

    unsigned short* QKVT = wt;                  // [2304][768]
    unsigned short* WOT  = wt + 1769472;        // [768][768]
    unsigned short* W1T  = wt + 2359296;        // [3072][768]
    unsigned short* W2T  = wt + 4718592;        // [768][3072]

    float* attn_out = out + XSZ;

    embed_kernel<<<ROWS, 256, 0, stream>>>(toks, emb, pos, x, xb);

    for (int l = 0; l < NL; ++l) {
        prep_weights<<<6912, 256, 0, stream>>>(
            wq + (size_t)l * DM * DM, wk + (size_t)l * DM * DM,
            wv + (size_t)l * DM * DM, wo + (size_t)l * DM * DM,
            w1 + (size_t)l * DM * DFF, w2 + (size_t)l * DFF * DM, wt);

        // merged QKV projection: N=2304 -> qb | kbuf | vb (row-major bf16)
        gemm_bt<4><<<dim3(18, 32), 256, 0, stream>>>(xb, QKVT, nullptr, qb, DM, DM, DM, DM);
        transpose_v<<<dim3(24, 128), 256, 0, stream>>>(vb, vt);

        float* attnL = attn_out + (size_t)l * ATTN_L;
        attn_fused<<<dim3(SS / 16, BB * NH), 256, 0, stream>>>(qb, kbuf, vt, amask, attnL, cb);

        // output projection + LN1
        gemm_bt<1><<<dim3(6, 32), 256, 0, stream>>>(cb, WOT, nullptr, qb, DM, DM, DM, DM);
        add_ln_kernel<<<ROWS, 256, 0, stream>>>(qb, x, ln1g + l * DM, ln1b + l * DM, x, xb);

        // FFN + LN2
        gemm_bt<2><<<dim3(24, 32), 256, 0, stream>>>(xb, W1T, b1 + (size_t)l * DFF, ffb, DM, DM, DM, DFF);
        gemm_bt<1><<<dim3(6, 32), 256, 0, stream>>>(ffb, W2T, b2 + (size_t)l * DM, qb, DFF, DFF, DFF, DM);

        float* xdst = (l == NL - 1) ? out : x;
        add_ln_kernel<<<ROWS, 256, 0, stream>>>(qb, x, ln2g + l * DM, ln2b + l * DM, xdst, xb);
    }
}

// Round 6
// 874.993 us; speedup vs baseline: 4.0623x; 1.0563x over previous
//
#include <hip/hip_runtime.h>
#include <math.h>

#define DM 768
#define NH 12
#define DK 64
#define DFF 3072
#define BB 2
#define SS 2048
#define NL 2

typedef __attribute__((ext_vector_type(8))) short short8;
typedef __attribute__((ext_vector_type(4))) float f32x4;

__device__ inline unsigned short f2bf(float f) {
    unsigned int u = __float_as_uint(f);
    u += 0x7fffu + ((u >> 16) & 1u);
    return (unsigned short)(u >> 16);
}
__device__ inline float bf2f(unsigned short h) {
    return __uint_as_float(((unsigned int)h) << 16);
}

#define GL16(g, l) __builtin_amdgcn_global_load_lds( \
    (const __attribute__((address_space(1))) void*)(g), \
    (__attribute__((address_space(3))) void*)(l), 16, 0, 0)

// ---------------- embed + positional (f32 + bf16 outputs) ----------------
__global__ __launch_bounds__(256) void embed_kernel(
    const int* __restrict__ toks, const float* __restrict__ emb,
    const float* __restrict__ pos, float* __restrict__ x,
    unsigned short* __restrict__ xb)
{
    int rs = blockIdx.x;
    int s = rs & (SS - 1);
    int tok = toks[rs];
    int t = threadIdx.x;
    const float* e = emb + (size_t)tok * DM;
    const float* p = pos + (size_t)s * DM;
    float* xr = x + (size_t)rs * DM;
    unsigned short* xbr = xb + (size_t)rs * DM;
#pragma unroll
    for (int i = 0; i < 3; ++i) {
        int c = t + 256 * i;
        float v = e[c] + p[c];
        xr[c] = v;
        xbr[c] = f2bf(v);
    }
}

// ---------------- batched weight transpose-convert, BOTH layers, 1 launch ---
// per layer 6912 tiles: wq(576) wk(576) wv(576) wo(576) w1(2304) w2(2304)
// per-layer dst: QKVT[2304][768] | WOT[768][768] | W1T[3072][768] | W2T[768][3072]
__global__ __launch_bounds__(256) void prep_weights(
    const float* __restrict__ wq, const float* __restrict__ wk,
    const float* __restrict__ wv, const float* __restrict__ wo,
    const float* __restrict__ w1, const float* __restrict__ w2,
    unsigned short* __restrict__ wt)
{
    __shared__ float tile[32][33];
    int id = blockIdx.x;
    int l = id / 6912; id -= l * 6912;
    unsigned short* wtl = wt + (size_t)l * 7077888;
    const float* src; unsigned short* dst; int Kd, Nd, nt, kt;
    if (id < 2304) {
        int m = id / 576, r = id % 576;
        src = ((m == 0) ? wq : (m == 1) ? wk : (m == 2) ? wv : wo) + (size_t)l * DM * DM;
        dst = wtl + (size_t)m * 589824;
        Kd = 768; Nd = 768; nt = r / 24; kt = r % 24;
    } else if (id < 4608) {
        int r = id - 2304;
        src = w1 + (size_t)l * DM * DFF; dst = wtl + 2359296; Kd = 768; Nd = 3072;
        nt = r / 24; kt = r % 24;
    } else {
        int r = id - 4608;
        src = w2 + (size_t)l * DFF * DM; dst = wtl + 4718592; Kd = 3072; Nd = 768;
        nt = r / 96; kt = r % 96;
    }
    int n0 = nt * 32, k0 = kt * 32;
    int c = threadIdx.x & 31, rr = threadIdx.x >> 5;
#pragma unroll
    for (int i = 0; i < 32; i += 8)
        tile[rr + i][c] = src[(size_t)(k0 + rr + i) * Nd + n0 + c];
    __syncthreads();
#pragma unroll
    for (int i = 0; i < 32; i += 8)
        dst[(size_t)(n0 + rr + i) * Kd + k0 + c] = f2bf(tile[c][rr + i]);
}

// ---------------- V transpose: vb[b*S+s][DM] bf16 -> vt[b][DM][S] bf16 ------
__global__ __launch_bounds__(256) void transpose_v(
    const unsigned short* __restrict__ vb, unsigned short* __restrict__ vt)
{
    __shared__ unsigned short tile[32][33];
    int c0 = blockIdx.x * 32;
    int r0 = blockIdx.y * 32;
    int c = threadIdx.x & 31, rr = threadIdx.x >> 5;
#pragma unroll
    for (int i = 0; i < 32; i += 8)
        tile[rr + i][c] = vb[(size_t)(r0 + rr + i) * DM + c0 + c];
    __syncthreads();
    int b = r0 >> 11;
    int s0 = r0 & 2047;
#pragma unroll
    for (int i = 0; i < 32; i += 8)
        vt[((size_t)b * DM + c0 + rr + i) * SS + s0 + c] = tile[c][rr + i];
}

// ---------------- MFMA GEMM: C[M,N] = A[M,K](bf16) @ Bt[N,K](bf16)^T --------
// 128x128 tile, BK=32, 256 thr = 4 waves (2x2), 4x4 16x16x32 frags per wave.
// OUT_MODE: 0=f32 split-K partial (blockIdx.z slice, C at z*4096*ldc),
//           1=bf16, 2=bf16+relu, 4=bf16 into 3 consecutive [4096][768] mats
template<int OUT_MODE>
__global__ __launch_bounds__(256) void gemm_bt(
    const unsigned short* __restrict__ A, const unsigned short* __restrict__ Bt,
    const float* __restrict__ bias, void* __restrict__ Cv,
    int K, int lda, int ldb, int ldc)
{
    __shared__ unsigned short As[128 * 32];
    __shared__ unsigned short Bs[128 * 32];
    const int t = threadIdx.x;
    const int row0 = blockIdx.y * 128;
    const int col0 = blockIdx.x * 128;
    const int z = (OUT_MODE == 0) ? blockIdx.z : 0;
    if (OUT_MODE == 0) { A += (size_t)z * K; Bt += (size_t)z * K; }
    const int lane = t & 63, wid = t >> 6;
    const int wr = wid >> 1, wc = wid & 1;
    const int half = lane >> 4, lr = lane & 15;
    f32x4 acc[4][4] = {};

    const int o = t * 16;
    const int srow = o >> 6;
    const int skb = (o & 63) >> 1;

    for (int k0 = 0; k0 < K; k0 += 32) {
        GL16(A + (size_t)(row0 + srow) * lda + k0 + skb, (unsigned short*)As + o / 2);
        GL16(A + (size_t)(row0 + 64 + srow) * lda + k0 + skb, (unsigned short*)As + 2048 + o / 2);
        GL16(Bt + (size_t)(col0 + srow) * ldb + k0 + skb, (unsigned short*)Bs + o / 2);
        GL16(Bt + (size_t)(col0 + 64 + srow) * ldb + k0 + skb, (unsigned short*)Bs + 2048 + o / 2);
        __syncthreads();
        short8 af[4], bfr[4];
#pragma unroll
        for (int m = 0; m < 4; ++m)
            af[m] = *(const short8*)&As[(wr * 64 + m * 16 + lr) * 32 + half * 8];
#pragma unroll
        for (int n = 0; n < 4; ++n)
            bfr[n] = *(const short8*)&Bs[(wc * 64 + n * 16 + lr) * 32 + half * 8];
#pragma unroll
        for (int m = 0; m < 4; ++m)
#pragma unroll
            for (int n = 0; n < 4; ++n)
                acc[m][n] = __builtin_amdgcn_mfma_f32_16x16x32_bf16(af[m], bfr[n], acc[m][n], 0, 0, 0);
        __syncthreads();
    }

#pragma unroll
    for (int m = 0; m < 4; ++m) {
#pragma unroll
        for (int n = 0; n < 4; ++n) {
            const int cidx = col0 + wc * 64 + n * 16 + lr;
            const float bv = bias ? bias[cidx] : 0.0f;
#pragma unroll
            for (int j = 0; j < 4; ++j) {
                const int r = row0 + wr * 64 + m * 16 + half * 4 + j;
                float v = acc[m][n][j] + bv;
                if (OUT_MODE == 2) v = fmaxf(v, 0.0f);
                if (OUT_MODE == 0) {
                    ((float*)Cv)[((size_t)z * 4096 + r) * ldc + cidx] = v;
                } else if (OUT_MODE == 4) {
                    int mi = (cidx >= 1536) ? 2 : (cidx >= 768 ? 1 : 0);
                    int cl = cidx - mi * 768;
                    ((unsigned short*)Cv)[((size_t)mi * 4096 + r) * 768 + cl] = f2bf(v);
                } else {
                    ((unsigned short*)Cv)[(size_t)r * ldc + cidx] = f2bf(v);
                }
            }
        }
    }
}

// ---------------- fused attention v3: QBLK=32, 2-pass, dbuf K/V, single E ---
// 1536 blocks (1D), XCD-affinity: each XCD owns 3 complete (b,h) heads.
// Pass A: row-sums of exp(masked scaled scores). Pass B: normalized E ->
// P-write (nontemporal f32) + PV MFMA. 4 waves; wave w owns d-cols w*16..+15.
__global__ __launch_bounds__(256) void attn_fused(
    const unsigned short* __restrict__ qg, const unsigned short* __restrict__ kg,
    const unsigned short* __restrict__ vt, const int* __restrict__ amask,
    float* __restrict__ attnL, unsigned short* __restrict__ cb)
{
    __shared__ unsigned short Ks[2][128 * 64];   // 2x16KB [krow][dk], swizzled
    __shared__ unsigned short Vs[2][64 * 128];   // 2x16KB [d][s], swizzled
    __shared__ unsigned short Es[32 * 128];      // 8KB [qrow][kcol], swizzled
    __shared__ float redsum[4][32];
    __shared__ float invs[32];

    const int t = threadIdx.x;
    // XCD affinity: id%8 = XCD (dispatch round-robin); give each XCD 3 heads
    const int id = blockIdx.x;              // 0..1535
    const int xcd = id & 7, idx = id >> 3;  // idx 0..191
    const int bh = xcd * 3 + (idx >> 6);    // 24 heads total
    const int qt = idx & 63;
    const int b = bh / NH, h = bh % NH;
    const int q0 = qt * 32;
    const int lane = t & 63, w = t >> 6;
    const int half = lane >> 4, lr = lane & 15;
    const int* am = amask + b * SS;

    // Q A-frags: afq[m][ks] -> rows q0+m*16+lr, k = ks*32 + half*8 .. +8
    const unsigned short* qbase = qg + ((size_t)b * SS + q0 + lr) * DM + h * DK + half * 8;
    short8 afq[2][2];
    afq[0][0] = *(const short8*)(qbase);
    afq[0][1] = *(const short8*)(qbase + 32);
    afq[1][0] = *(const short8*)(qbase + 16 * DM);
    afq[1][1] = *(const short8*)(qbase + 16 * DM + 32);

    const unsigned short* Kg = kg + (size_t)b * SS * DM + h * DK;
    const unsigned short* Vg = vt + ((size_t)b * DM + h * DK) * SS;

#define STAGE_K(kt, buf) { \
    _Pragma("unroll") \
    for (int r_ = 0; r_ < 4; ++r_) { \
        int o_ = r_ * 4096 + t * 16; \
        int krow_ = o_ >> 7; \
        int cp_ = (o_ >> 4) & 7; \
        GL16(Kg + (size_t)((kt) * 128 + krow_) * DM + ((cp_ ^ (krow_ & 7)) << 3), (char*)Ks[buf] + o_); \
    } }
#define STAGE_V(kt, buf) { \
    _Pragma("unroll") \
    for (int r_ = 0; r_ < 4; ++r_) { \
        int o_ = r_ * 4096 + t * 16; \
        int d_ = o_ >> 8; \
        int cp_ = (o_ >> 4) & 15; \
        GL16(Vg + (size_t)d_ * SS + (kt) * 128 + ((cp_ ^ (d_ & 7)) << 3), (char*)Vs[buf] + o_); \
    } }

    // ================= pass A: row sums =================
    float vsum[2][4] = {};
    STAGE_K(0, 0);
    for (int kt = 0; kt < 16; ++kt) {
        asm volatile("s_waitcnt vmcnt(0)" ::: "memory");
        __builtin_amdgcn_s_barrier();
        if (kt < 15) STAGE_K(kt + 1, (kt + 1) & 1);
        const char* kbuf = (const char*)Ks[kt & 1];
#pragma unroll
        for (int nn = 0; nn < 2; ++nn) {
            const int krl = w * 32 + nn * 16 + lr;
            const char* kr = kbuf + krl * 128;
            const int ksw = krl & 7;
            short8 bk0 = *(const short8*)(kr + ((half ^ ksw) << 4));
            short8 bk1 = *(const short8*)(kr + (((4 + half) ^ ksw) << 4));
            const int kpos = kt * 128 + krl;
            const bool pad = (am[kpos] == 0);
#pragma unroll
            for (int m = 0; m < 2; ++m) {
                f32x4 s = {};
                s = __builtin_amdgcn_mfma_f32_16x16x32_bf16(afq[m][0], bk0, s, 0, 0, 0);
                s = __builtin_amdgcn_mfma_f32_16x16x32_bf16(afq[m][1], bk1, s, 0, 0, 0);
#pragma unroll
                for (int j = 0; j < 4; ++j) {
                    int qpos = q0 + m * 16 + half * 4 + j;
                    if (pad || (kpos > qpos))   // FAITHFUL: keep where pad||future
                        vsum[m][j] += __expf(0.125f * s[j]);
                }
            }
        }
    }
    __syncthreads();

#pragma unroll
    for (int m = 0; m < 2; ++m)
#pragma unroll
        for (int j = 0; j < 4; ++j) {
            vsum[m][j] += __shfl_xor(vsum[m][j], 1, 64);
            vsum[m][j] += __shfl_xor(vsum[m][j], 2, 64);
            vsum[m][j] += __shfl_xor(vsum[m][j], 4, 64);
            vsum[m][j] += __shfl_xor(vsum[m][j], 8, 64);
        }
    if (lr == 0) {
#pragma unroll
        for (int m = 0; m < 2; ++m)
#pragma unroll
            for (int j = 0; j < 4; ++j)
                redsum[w][m * 16 + half * 4 + j] = vsum[m][j];
    }
    __syncthreads();
    if (t < 32) {
        float rs = redsum[0][t] + redsum[1][t] + redsum[2][t] + redsum[3][t];
        invs[t] = (rs > 0.0f) ? 1.0f / rs : 0.0f;
    }
    __syncthreads();

    // ================= pass B: normalized E -> P + PV =================
    f32x4 ctxa[2] = {};
    float* ab = attnL + ((size_t)bh * SS + q0) * SS;
    STAGE_K(0, 0);
    STAGE_V(0, 0);
    for (int kt = 0; kt < 16; ++kt) {
        if (kt == 0) {
            asm volatile("s_waitcnt vmcnt(0)" ::: "memory");
        } else {
            asm volatile("s_waitcnt vmcnt(4)" ::: "memory");  // 8 loads done, ≤4 P-stores in flight
        }
        __builtin_amdgcn_s_barrier();
        if (kt < 15) { STAGE_K(kt + 1, (kt + 1) & 1); STAGE_V(kt + 1, (kt + 1) & 1); }
        const char* kbuf = (const char*)Ks[kt & 1];
#pragma unroll
        for (int nn = 0; nn < 2; ++nn) {
            const int krl = w * 32 + nn * 16 + lr;
            const char* kr = kbuf + krl * 128;
            const int ksw = krl & 7;
            short8 bk0 = *(const short8*)(kr + ((half ^ ksw) << 4));
            short8 bk1 = *(const short8*)(kr + (((4 + half) ^ ksw) << 4));
            const int kpos = kt * 128 + krl;
            const bool pad = (am[kpos] == 0);
#pragma unroll
            for (int m = 0; m < 2; ++m) {
                f32x4 s = {};
                s = __builtin_amdgcn_mfma_f32_16x16x32_bf16(afq[m][0], bk0, s, 0, 0, 0);
                s = __builtin_amdgcn_mfma_f32_16x16x32_bf16(afq[m][1], bk1, s, 0, 0, 0);
#pragma unroll
                for (int j = 0; j < 4; ++j) {
                    int row = m * 16 + half * 4 + j;
                    int qpos = q0 + row;
                    bool keep = pad || (kpos > qpos);
                    float e = keep ? __expf(0.125f * s[j]) * invs[row] : 0.0f;
                    *((unsigned short*)((char*)Es + row * 256 + ((krl * 2) ^ ((row & 7) << 4)))) = f2bf(e);
                }
            }
        }
        asm volatile("s_waitcnt lgkmcnt(0)" ::: "memory");   // E-writes visible
        __builtin_amdgcn_s_barrier();

        // PV: ctx += E[32x128] @ V[128x64]; wave w owns d-cols w*16..+15
        const char* vbuf = (const char*)Vs[kt & 1];
#pragma unroll
        for (int ks = 0; ks < 4; ++ks) {
            const int dl = w * 16 + lr;
            const int cv = ks * 4 + half;
            short8 bv = *(const short8*)(vbuf + dl * 256 + ((cv ^ (dl & 7)) << 4));
#pragma unroll
            for (int m = 0; m < 2; ++m) {
                short8 ae = *(const short8*)((const char*)Es + (m * 16 + lr) * 256 +
                                             ((ks * 64 + half * 16) ^ ((lr & 7) << 4)));
                ctxa[m] = __builtin_amdgcn_mfma_f32_16x16x32_bf16(ae, bv, ctxa[m], 0, 0, 0);
            }
        }

        // P-write: 256 threads cover 32 rows x 8 chunks (16 f32 each), NT
        {
            const int prow = t >> 3, pchunk = t & 7;
            const char* erow = (const char*)Es + prow * 256;
            const int swz = (prow & 7) << 4;
            short8 e0 = *(const short8*)(erow + ((pchunk * 32) ^ swz));
            short8 e1 = *(const short8*)(erow + ((pchunk * 32 + 16) ^ swz));
            float* dst = ab + (size_t)prow * SS + kt * 128 + pchunk * 16;
            f32x4 o0, o1, o2, o3;
            o0[0] = bf2f((unsigned short)e0[0]); o0[1] = bf2f((unsigned short)e0[1]);
            o0[2] = bf2f((unsigned short)e0[2]); o0[3] = bf2f((unsigned short)e0[3]);
            o1[0] = bf2f((unsigned short)e0[4]); o1[1] = bf2f((unsigned short)e0[5]);
            o1[2] = bf2f((unsigned short)e0[6]); o1[3] = bf2f((unsigned short)e0[7]);
            o2[0] = bf2f((unsigned short)e1[0]); o2[1] = bf2f((unsigned short)e1[1]);
            o2[2] = bf2f((unsigned short)e1[2]); o2[3] = bf2f((unsigned short)e1[3]);
            o3[0] = bf2f((unsigned short)e1[4]); o3[1] = bf2f((unsigned short)e1[5]);
            o3[2] = bf2f((unsigned short)e1[6]); o3[3] = bf2f((unsigned short)e1[7]);
            __builtin_nontemporal_store(o0, (f32x4*)dst);
            __builtin_nontemporal_store(o1, (f32x4*)(dst + 4));
            __builtin_nontemporal_store(o2, (f32x4*)(dst + 8));
            __builtin_nontemporal_store(o3, (f32x4*)(dst + 12));
        }
    }

    // ctx write (already normalized)
#pragma unroll
    for (int m = 0; m < 2; ++m)
#pragma unroll
        for (int j = 0; j < 4; ++j) {
            int row = m * 16 + half * 4 + j;
            cb[((size_t)b * SS + q0 + row) * DM + h * DK + w * 16 + lr] = f2bf(ctxa[m][j]);
        }
#undef STAGE_K
#undef STAGE_V
}

// ------- residual add (two f32 split-K partials + opt bias) + layernorm ----
__global__ __launch_bounds__(256) void add_ln_kernel(
    const float* __restrict__ p0, const float* __restrict__ p1,
    const float* __restrict__ bias, const float* __restrict__ xin,
    const float* __restrict__ g, const float* __restrict__ bta,
    float* __restrict__ xout, unsigned short* __restrict__ xbout)
{
    int row = blockIdx.x;
    int t = threadIdx.x;
    const float* a0 = p0 + (size_t)row * DM;
    const float* a1 = p1 + (size_t)row * DM;
    const float* xr = xin + (size_t)row * DM;
    float* orow = xout + (size_t)row * DM;
    unsigned short* obr = xbout + (size_t)row * DM;
    __shared__ float red[256];
    float v[3];
    float sum = 0.0f;
#pragma unroll
    for (int i = 0; i < 3; ++i) {
        int c = t + 256 * i;
        v[i] = a0[c] + a1[c] + xr[c] + (bias ? bias[c] : 0.0f);
        sum += v[i];
    }
    red[t] = sum;
    __syncthreads();
    for (int s = 128; s > 0; s >>= 1) {
        if (t < s) red[t] += red[t + s];
        __syncthreads();
    }
    float mean = red[0] * (1.0f / DM);
    __syncthreads();
    float sq = 0.0f;
#pragma unroll
    for (int i = 0; i < 3; ++i) {
        float d = v[i] - mean;
        sq += d * d;
    }
    red[t] = sq;
    __syncthreads();
    for (int s = 128; s > 0; s >>= 1) {
        if (t < s) red[t] += red[t + s];
        __syncthreads();
    }
    float inv = 1.0f / sqrtf(red[0] * (1.0f / DM) + 1e-5f);
#pragma unroll
    for (int i = 0; i < 3; ++i) {
        int c = t + 256 * i;
        float ov = (v[i] - mean) * inv * g[c] + bta[c];
        orow[c] = ov;
        obr[c] = f2bf(ov);
    }
}

extern "C" void kernel_launch(void* const* d_in, const int* in_sizes, int n_in,
                              void* d_out, int out_size, void* d_ws, size_t ws_size,
                              hipStream_t stream)
{
    const int*   toks  = (const int*)d_in[0];
    const int*   amask = (const int*)d_in[1];
    const float* emb   = (const float*)d_in[2];
    const float* pos   = (const float*)d_in[3];
    const float* wq    = (const float*)d_in[4];
    const float* wk    = (const float*)d_in[5];
    const float* wv    = (const float*)d_in[6];
    const float* wo    = (const float*)d_in[7];
    const float* ln1g  = (const float*)d_in[8];
    const float* ln1b  = (const float*)d_in[9];
    const float* w1    = (const float*)d_in[10];
    const float* b1    = (const float*)d_in[11];
    const float* w2    = (const float*)d_in[12];
    const float* b2    = (const float*)d_in[13];
    const float* ln2g  = (const float*)d_in[14];
    const float* ln2b  = (const float*)d_in[15];

    float* out = (float*)d_out;
    char*  wsb = (char*)d_ws;

    const size_t ROWS = (size_t)BB * SS;                 // 4096
    const size_t XSZ  = ROWS * DM;                       // 3,145,728
    const size_t ATTN_L = (size_t)BB * NH * SS * SS;     // 100,663,296

    float*          x    = (float*)(wsb);                          // 12.58 MB
    unsigned short* xb   = (unsigned short*)(wsb + 12582912);      // 6.29 MB
    unsigned short* qb   = (unsigned short*)(wsb + 18874368);      // 6.29 MB (QKV out 0)
    unsigned short* kbuf = (unsigned short*)(wsb + 25165824);      // 6.29 MB (QKV out 1)
    unsigned short* vb   = (unsigned short*)(wsb + 31457280);      // 6.29 MB (QKV out 2)
    unsigned short* cb   = (unsigned short*)(wsb + 37748736);      // 6.29 MB
    float*          p0   = (float*)(wsb + 44040192);               // 12.58 MB
    float*          p1   = (float*)(wsb + 56623104);               // 12.58 MB
    unsigned short* vt   = (unsigned short*)(wsb + 69206016);      // aliases ffb
    unsigned short* ffb  = (unsigned short*)(wsb + 69206016);      // 25.17 MB
    unsigned short* wt   = (unsigned short*)(wsb + 94371840);      // 28.31 MB (both layers)

    float* attn_out = out + XSZ;

    embed_kernel<<<ROWS, 256, 0, stream>>>(toks, emb, pos, x, xb);
    prep_weights<<<13824, 256, 0, stream>>>(wq, wk, wv, wo, w1, w2, wt);

    for (int l = 0; l < NL; ++l) {
        unsigned short* QKVT = wt + (size_t)l * 7077888;
        unsigned short* WOT  = QKVT + 1769472;
        unsigned short* W1T  = QKVT + 2359296;
        unsigned short* W2T  = QKVT + 4718592;

        // merged QKV projection: N=2304 -> qb | kbuf | vb (row-major bf16)
        gemm_bt<4><<<dim3(18, 32), 256, 0, stream>>>(xb, QKVT, nullptr, qb, DM, DM, DM, DM);
        transpose_v<<<dim3(24, 128), 256, 0, stream>>>(vb, vt);

        float* attnL = attn_out + (size_t)l * ATTN_L;
        attn_fused<<<1536, 256, 0, stream>>>(qb, kbuf, vt, amask, attnL, cb);

        // output projection (split-K=2, f32 partials) + LN1
        gemm_bt<0><<<dim3(6, 32, 2), 256, 0, stream>>>(cb, WOT, nullptr, p0, 384, DM, DM, DM);
        add_ln_kernel<<<ROWS, 256, 0, stream>>>(p0, p0 + XSZ, nullptr, x,
                                                ln1g + l * DM, ln1b + l * DM, x, xb);

        // FFN: W1+relu, W2 (split-K=2) + LN2 (bias b2 folded into LN)
        gemm_bt<2><<<dim3(24, 32), 256, 0, stream>>>(xb, W1T, b1 + (size_t)l * DFF, ffb, DM, DM, DM, DFF);
        gemm_bt<0><<<dim3(6, 32, 2), 256, 0, stream>>>(ffb, W2T, nullptr, p0, 1536, DFF, DFF, DM);

        float* xdst = (l == NL - 1) ? out : x;
        add_ln_kernel<<<ROWS, 256, 0, stream>>>(p0, p0 + XSZ, b2 + (size_t)l * DM, x,
                                                ln2g + l * DM, ln2b + l * DM, xdst, xb);
    }
    (void)p1;
}